// Round 14
// baseline (391.706 us; speedup 1.0000x reference)
//
#include <hip/hip_runtime.h>
#include <math.h>

#define NB 16
#define INW 256
#define GN 100
#define NV (GN*GN)          // 10000
#define NPROB (NB*2)        // 32
#define K_TOP 20
#define HSZ 8192
#define KB 64               // positional buckets per problem
#define SNAPN 8             // snapshots (every 8 buckets)
#define RCAP 3072           // max regions per problem
#define MYCAP 128           // max edges per bucket
#define LISTCAP 3072        // max bars per problem
#define RBLK 625            // resize blocks (NB*NV/256)

// ws layout
#define OFF_RES   0               // NB*NV f32 = 640000
#define OFF_DENSE 1280000         // NPROB*NV u16 (alive until hash_k)
#define OFF_STATE 0               // overlay: NPROB*SNAPN*RCAP u16 = 1572864 (written by sortcc, after hash)
#define OFF_ROOTV 1920000         // NPROB*RCAP u16 = 196608
#define OFF_D2B   2116608         // NPROB*RCAP f32 = 393216
#define OFF_TAB   2509824         // NPROB*HSZ u64 = 2097152 (hash table -> sorted edges)
#define OFF_ECNT  4606976         // NPROB u32
#define OFF_RCNT  4607104         // NPROB u32
#define OFF_LCNT  4607232         // NPROB u32
#define OFF_LIST  4607360         // NPROB*LISTCAP f32 = 393216
#define OFF_PART  5000576         // NPROB f32
#define OFF_FLAB  5000704         // NPROB*NV u16 = 640000 (final labels)

__device__ __forceinline__ int imin(int a, int b){ return a < b ? a : b; }
__device__ __forceinline__ int imax(int a, int b){ return a > b ? a : b; }

__device__ __forceinline__ unsigned mono32(float f){
  unsigned b = __float_as_uint(f);
  return (b & 0x80000000u) ? ~b : (b | 0x80000000u);
}
__device__ __forceinline__ float unmono(unsigned m){
  unsigned b = (m & 0x80000000u) ? (m ^ 0x80000000u) : ~m;
  return __uint_as_float(b);
}

__device__ __forceinline__ unsigned uf_find(volatile unsigned* par, unsigned x){
  unsigned p = par[x];
  while (p != x) {
    unsigned g = par[p];
    if (g != p) par[x] = g;
    x = g;
    p = par[x];
  }
  return x;
}
__device__ __forceinline__ void uf_union(volatile unsigned* vpar, unsigned* par,
                                         unsigned a, unsigned b){
  while (1) {
    unsigned ra = uf_find(vpar, a);
    unsigned rb = uf_find(vpar, b);
    if (ra == rb) break;
    unsigned lo = (ra < rb) ? ra : rb, hi = (ra < rb) ? rb : ra;
    if (atomicCAS(&par[hi], hi, lo) == hi) break;
    a = lo; b = hi;
  }
}

__device__ __forceinline__ void cub_w(int i, int& j0, float w[4]) {
  double inv = (double)INW / (double)GN;
  double sf  = ((double)i + 0.5) * inv - 0.5;
  j0 = (int)floor(sf) - 1;
  double wd[4]; double s = 0.0;
  #pragma unroll
  for (int k = 0; k < 4; ++k) {
    int j = j0 + k;
    double t = fabs(sf - (double)j);
    double v;
    if (t < 1.0)      v = ((1.5*t - 2.5)*t)*t + 1.0;
    else if (t < 2.0) v = ((-0.5*t + 2.5)*t - 4.0)*t + 2.0;
    else              v = 0.0;
    if (j < 0 || j >= INW) v = 0.0;
    wd[k] = v; s += v;
  }
  #pragma unroll
  for (int k = 0; k < 4; ++k) w[k] = (float)(wd[k] / s);
}

// ---------------------------------------------------------------------------
// Kernel 1: bicubic resize (blocks 0..624) + per-problem init (blocks 625+)
// ---------------------------------------------------------------------------
__global__ __launch_bounds__(256) void resize_init_k(const float* __restrict__ in,
                                                     float* ws, float* out) {
  int tid = threadIdx.x;
  if (blockIdx.x >= RBLK) {
    int p = blockIdx.x - RBLK;
    unsigned long long* tab = (unsigned long long*)((char*)ws + OFF_TAB) + (size_t)p * HSZ;
    for (int i = tid; i < HSZ; i += 256) tab[i] = 0ull;
    if (tid == 0) {
      ((unsigned*)((char*)ws + OFF_ECNT))[p] = 0u;
      ((unsigned*)((char*)ws + OFF_RCNT))[p] = 0u;
      ((unsigned*)((char*)ws + OFF_LCNT))[p] = 0u;
      if (p == 0) out[0] = 0.f;
    }
    return;
  }
  float* outp = (float*)((char*)ws + OFF_RES);
  int idx = blockIdx.x * 256 + tid;
  if (idx >= NB * NV) return;
  int b = idx / NV; int rem = idx - b * NV;
  int i = rem / GN; int j = rem - i * GN;
  const float* img = in + (size_t)b * INW * INW;
  int r0, c0; float wr[4], wc[4];
  cub_w(i, r0, wr);
  cub_w(j, c0, wc);
  float acc = 0.f;
  #pragma unroll
  for (int kr = 0; kr < 4; ++kr) {
    int rr = imin(imax(r0 + kr, 0), INW - 1);
    const float* row = img + rr * INW;
    int c0c = imin(imax(c0 + 0, 0), INW - 1);
    int c1c = imin(imax(c0 + 1, 0), INW - 1);
    int c2c = imin(imax(c0 + 2, 0), INW - 1);
    int c3c = imin(imax(c0 + 3, 0), INW - 1);
    float rs = wc[0]*row[c0c] + wc[1]*row[c1c] + wc[2]*row[c2c] + wc[3]*row[c3c];
    acc += wr[kr] * rs;
  }
  outp[idx] = acc;
}

// ---------------------------------------------------------------------------
// Kernel 2: FUSED steepest-earlier-neighbor + LDS chase + root compaction.
// One block per problem; sm (40KB) + lab (20KB) in LDS.
// ---------------------------------------------------------------------------
__global__ __launch_bounds__(256) void spnchase_k(float* ws) {
  __shared__ unsigned sm[NV];                 // 40KB
  __shared__ unsigned short lab[NV];          // 20KB
  __shared__ unsigned cnt[256];
  int p = blockIdx.x, tid = threadIdx.x;
  int samp = p >> 1, neg = p & 1;
  const float* res = (const float*)((const char*)ws + OFF_RES) + samp * NV;
  unsigned short* flab = (unsigned short*)((char*)ws + OFF_FLAB) + (size_t)p * NV;
  unsigned short* rootv = (unsigned short*)((char*)ws + OFF_ROOTV) + (size_t)p * RCAP;
  unsigned* rcnt = (unsigned*)((char*)ws + OFF_RCNT);
  float sgn = neg ? -1.f : 1.f;
  for (int i = tid; i < NV; i += 256) sm[i] = mono32(sgn * res[i]);
  __syncthreads();
  const int nd = neg ? 4 : 6;
  for (int v = tid; v < NV; v += 256) {
    int r = v / GN, c = v - r * GN;
    unsigned long long best = ((unsigned long long)sm[v] << 32) | (unsigned)~(unsigned)v;
    unsigned bi = (unsigned)v;
    bool cb[6] = { c < GN-1, c > 0, r < GN-1, r > 0,
                   (r < GN-1) && (c < GN-1), (r > 0) && (c > 0) };
    int  off[6] = { 1, -1, GN, -GN, GN+1, -(GN+1) };
    #pragma unroll
    for (int d = 0; d < 6; ++d) {
      if (d < nd && cb[d]) {
        unsigned y = (unsigned)(v + off[d]);
        unsigned long long o = ((unsigned long long)sm[y] << 32) | (unsigned)~y;
        if (o > best) { best = o; bi = y; }
      }
    }
    lab[v] = (unsigned short)bi;
  }
  __syncthreads();
  for (int v = tid; v < NV; v += 256) {
    unsigned r = lab[v];
    while (1) { unsigned n = lab[r]; if (n == r) break; r = n; }
    lab[v] = (unsigned short)r;               // compression (ancestor-safe)
    flab[v] = (unsigned short)r;
  }
  __syncthreads();
  unsigned my = 0;
  for (int v = tid; v < NV; v += 256) if (lab[v] == (unsigned short)v) ++my;
  cnt[tid] = my;
  __syncthreads();
  for (int off = 1; off < 256; off <<= 1) {
    unsigned t = (tid >= off) ? cnt[tid - off] : 0u;
    __syncthreads();
    cnt[tid] += t;
    __syncthreads();
  }
  unsigned base = cnt[tid] - my;
  for (int v = tid; v < NV; v += 256) {
    if (lab[v] == (unsigned short)v) {
      if (base < RCAP) rootv[base] = (unsigned short)v;
      ++base;
    }
  }
  if (tid == 255) rcnt[p] = (cnt[255] > RCAP) ? RCAP : cnt[255];
}

// ---------------------------------------------------------------------------
// Kernel 3: rank roots desc (elder order) -> dense ids + birth table.
// ---------------------------------------------------------------------------
__global__ __launch_bounds__(256) void rank_root_k(float* ws) {
  __shared__ unsigned long long ro[RCAP];
  __shared__ unsigned short rv_sh[RCAP];
  int p = blockIdx.x / 16, sl = blockIdx.x % 16, tid = threadIdx.x;
  int samp = p >> 1, neg = p & 1;
  const float* res = (const float*)((const char*)ws + OFF_RES) + samp * NV;
  const unsigned short* rootv = (const unsigned short*)((const char*)ws + OFF_ROOTV) + (size_t)p * RCAP;
  unsigned short* dense = (unsigned short*)((char*)ws + OFF_DENSE) + (size_t)p * NV;
  float* d2b = (float*)((char*)ws + OFF_D2B) + (size_t)p * RCAP;
  const unsigned* rcnt = (const unsigned*)((const char*)ws + OFF_RCNT);
  unsigned R = rcnt[p]; if (R > RCAP) R = RCAP;
  float sgn = neg ? -1.f : 1.f;
  for (unsigned i = tid; i < R; i += 256) {
    unsigned v = rootv[i];
    ro[i] = ((unsigned long long)mono32(sgn * res[v]) << 32) | (unsigned)~v;
    rv_sh[i] = (unsigned short)v;
  }
  __syncthreads();
  unsigned RS = (R + 15) / 16;
  unsigned lo = sl * RS, hi = lo + RS; if (hi > R) hi = R;
  for (unsigned i = lo + tid; i < hi; i += 256) {
    unsigned long long oi = ro[i];
    unsigned r = 0;
    for (unsigned j = 0; j < R; ++j) r += (ro[j] > oi) ? 1u : 0u;
    dense[rv_sh[i]] = (unsigned short)r;
    d2b[r] = unmono((unsigned)(oi >> 32));
  }
}

// ---------------------------------------------------------------------------
// Kernel 4: boundary-edge dedup into GLOBAL u64 hash table. 8 slices/problem.
// ---------------------------------------------------------------------------
__global__ __launch_bounds__(256) void hash_k(float* ws) {
  int p = blockIdx.x >> 3, sl = blockIdx.x & 7, tid = threadIdx.x;
  int samp = p >> 1, neg = p & 1;
  const float* res = (const float*)((const char*)ws + OFF_RES) + samp * NV;
  const unsigned short* flab = (const unsigned short*)((const char*)ws + OFF_FLAB) + (size_t)p * NV;
  const unsigned short* gdense = (const unsigned short*)((const char*)ws + OFF_DENSE) + (size_t)p * NV;
  unsigned long long* tab = (unsigned long long*)((char*)ws + OFF_TAB) + (size_t)p * HSZ;
  float sgn = neg ? -1.f : 1.f;
  int v0 = sl * (NV / 8), v1 = v0 + (NV / 8);
  for (int v = v0 + tid; v < v1; v += 256) {
    int r = v / GN, c = v - r * GN;
    unsigned a = gdense[flab[v]];
    unsigned sv = mono32(sgn * res[v]);
    bool vb[3] = { c < GN-1, r < GN-1, (!neg) && (r < GN-1) && (c < GN-1) };
    int  vo[3] = { 1, GN, GN+1 };
    #pragma unroll
    for (int d = 0; d < 3; ++d) {
      if (vb[d]) {
        unsigned w = (unsigned)(v + vo[d]);
        unsigned b = gdense[flab[w]];
        if (a != b) {
          unsigned sw = mono32(sgn * res[w]);
          unsigned ev = (sv < sw) ? sv : sw;
          unsigned dlo = (a < b) ? a : b, dhi = (a < b) ? b : a;
          unsigned pid = (dlo << 16) | dhi;
          unsigned long long packed = ((unsigned long long)ev << 32) | pid;
          unsigned h = (pid * 2654435761u) >> 19;
          for (int t = 0; t < HSZ; ++t) {
            unsigned long long cur = tab[h];
            if (cur == 0ull) {
              unsigned long long old = atomicCAS(&tab[h], 0ull, packed);
              if (old == 0ull) break;
              cur = old;
            }
            if ((unsigned)cur == pid) { atomicMax(&tab[h], packed); break; }
            h = (h + 1) & (HSZ - 1);
          }
        }
      }
    }
  }
}

// ---------------------------------------------------------------------------
// Kernel 5: FUSED gather + in-LDS radix sort (desc by ev) + prefix-CC
// snapshots. Parallel digit-scan; degenerate passes skipped.
// ---------------------------------------------------------------------------
__global__ __launch_bounds__(256) void sortcc_k(float* ws) {
  __shared__ unsigned long long bufA[HSZ];    // 64KB
  __shared__ unsigned long long bufB[HSZ];    // 64KB (par after sort)
  __shared__ unsigned cnt[16 * 256];          // 16KB
  __shared__ unsigned tot[16];
  __shared__ unsigned mc_sh;
  __shared__ int skip_sh;
  int p = blockIdx.x, tid = threadIdx.x;
  unsigned long long* tab = (unsigned long long*)((char*)ws + OFF_TAB) + (size_t)p * HSZ;
  unsigned short* state = (unsigned short*)((char*)ws + OFF_STATE) + (size_t)p * SNAPN * RCAP;
  unsigned* ecnt = (unsigned*)((char*)ws + OFF_ECNT);
  const unsigned* rcnt = (const unsigned*)((const char*)ws + OFF_RCNT);
  unsigned R = rcnt[p]; if (R > RCAP) R = RCAP;
  if (tid == 0) mc_sh = 0;
  __syncthreads();
  for (int i = tid; i < HSZ; i += 256) {
    unsigned long long x = tab[i];
    if (x != 0ull) { unsigned k = atomicAdd(&mc_sh, 1u); bufA[k] = x; }
  }
  __syncthreads();
  unsigned E = mc_sh;
  unsigned chunk = (E + 255) >> 8;
  unsigned lo = tid * chunk; if (lo > E) lo = E;
  unsigned hi = lo + chunk; if (hi > E) hi = E;
  unsigned long long* src = bufA;
  unsigned long long* dst = bufB;
  for (int pass = 0; pass < 8; ++pass) {
    int shift = 32 + pass * 4;
    #pragma unroll
    for (int s = 0; s < 16; ++s) cnt[s * 256 + tid] = 0;
    __syncthreads();
    for (unsigned i = lo; i < hi; ++i) {
      unsigned slot = 15u - ((unsigned)(src[i] >> shift) & 15u);
      cnt[slot * 256 + tid] += 1u;
    }
    unsigned myc[16];
    #pragma unroll
    for (int s = 0; s < 16; ++s) myc[s] = cnt[s * 256 + tid];
    __syncthreads();
    // parallel inclusive scan over tid for all 16 slots at once
    for (int off = 1; off < 256; off <<= 1) {
      unsigned add[16];
      #pragma unroll
      for (int s = 0; s < 16; ++s) add[s] = (tid >= off) ? cnt[s * 256 + tid - off] : 0u;
      __syncthreads();
      #pragma unroll
      for (int s = 0; s < 16; ++s) cnt[s * 256 + tid] += add[s];
      __syncthreads();
    }
    if (tid < 16) tot[tid] = cnt[tid * 256 + 255];   // per-slot totals
    __syncthreads();
    if (tid == 0) {
      int sk = 0;
      unsigned s = 0;
      #pragma unroll
      for (int d = 0; d < 16; ++d) {
        unsigned c = tot[d];
        if (c == E) sk = 1;
        tot[d] = s; s += c;
      }
      skip_sh = sk;
    }
    __syncthreads();
    if (skip_sh) continue;                            // all items share this digit
    // offset for this thread = tot[slot] + inclusive - own count
    #pragma unroll
    for (int s = 0; s < 16; ++s) cnt[s * 256 + tid] = tot[s] + cnt[s * 256 + tid] - myc[s];
    __syncthreads();
    for (unsigned i = lo; i < hi; ++i) {
      unsigned long long x = src[i];
      unsigned slot = 15u - ((unsigned)(x >> shift) & 15u);
      unsigned off = cnt[slot * 256 + tid];
      cnt[slot * 256 + tid] = off + 1u;
      dst[tot[slot] * 0 + off] = x;                   // off already includes base
    }
    __syncthreads();
    unsigned long long* t2 = src; src = dst; dst = t2;
  }
  for (unsigned i = tid; i < E; i += 256) tab[i] = src[i];
  if (tid == 0) ecnt[p] = E;
  __syncthreads();
  // keep sorted edges accessible: if src==bufB, par must live in bufA
  unsigned long long* edg = src;
  unsigned* par = (unsigned*)((src == bufA) ? bufB : bufA);
  for (unsigned d = tid; d < R; d += 256) par[d] = d;
  __syncthreads();
  volatile unsigned* vpar = par;
  unsigned cp = (E + KB - 1) / KB;
  for (int s = 0; s < SNAPN; ++s) {
    for (unsigned d = tid; d < R; d += 256) {
      unsigned r = d;
      while (vpar[r] != r) r = vpar[r];
      par[d] = r;
      state[s * RCAP + d] = (unsigned short)r;
    }
    __syncthreads();
    unsigned e0 = (unsigned)s * 8u * cp; if (e0 > E) e0 = E;
    unsigned e1 = (unsigned)(s + 1) * 8u * cp; if (e1 > E) e1 = E;
    for (unsigned e = e0 + tid; e < e1; e += 256) {
      unsigned pid = (unsigned)edg[e];
      uf_union(vpar, par, pid >> 16, pid & 0xffffu);
    }
    __syncthreads();
  }
}

// ---------------------------------------------------------------------------
// Kernel 6: bucketed Kruskal with speculative root hints.
// ---------------------------------------------------------------------------
__global__ __launch_bounds__(256) void kruskal_bucket_k(float* ws) {
  __shared__ unsigned par[RCAP];
  __shared__ unsigned hintR[MYCAP];
  __shared__ unsigned hintE[MYCAP];
  __shared__ float    hintB[MYCAP];
  __shared__ float    barbuf[MYCAP];
  __shared__ unsigned nb_sh, base_sh;
  int p = blockIdx.x / KB, bk = blockIdx.x % KB, tid = threadIdx.x;
  const unsigned long long* gedges = (const unsigned long long*)((const char*)ws + OFF_TAB) + (size_t)p * HSZ;
  const float* d2b = (const float*)((const char*)ws + OFF_D2B) + (size_t)p * RCAP;
  const unsigned short* state = (const unsigned short*)((const char*)ws + OFF_STATE) + (size_t)p * SNAPN * RCAP + (size_t)(bk >> 3) * RCAP;
  const unsigned* ecnt = (const unsigned*)((const char*)ws + OFF_ECNT);
  const unsigned* rcnt = (const unsigned*)((const char*)ws + OFF_RCNT);
  unsigned* lcnt = (unsigned*)((char*)ws + OFF_LCNT);
  float* glist = (float*)((char*)ws + OFF_LIST) + (size_t)p * LISTCAP;
  unsigned E = ecnt[p]; if (E > HSZ) E = HSZ;
  unsigned R = rcnt[p]; if (R > RCAP) R = RCAP;
  unsigned cp = (E + KB - 1) / KB;
  unsigned rep_lo = (unsigned)(bk & ~7) * cp; if (rep_lo > E) rep_lo = E;
  unsigned own_lo = (unsigned)bk * cp;        if (own_lo > E) own_lo = E;
  unsigned own_hi = own_lo + cp;              if (own_hi > E) own_hi = E;
  unsigned mc = own_hi - own_lo;
  for (unsigned d = tid; d < R; d += 256) par[d] = state[d];
  __syncthreads();
  volatile unsigned* vpar = par;
  for (unsigned e = rep_lo + tid; e < own_lo; e += 256) {
    unsigned pid = (unsigned)gedges[e];
    uf_union(vpar, par, pid >> 16, pid & 0xffffu);
  }
  __syncthreads();
  for (unsigned d = tid; d < R; d += 256) {
    unsigned r = d;
    while (vpar[r] != r) r = vpar[r];
    par[d] = r;
  }
  __syncthreads();
  if (tid < mc) {
    unsigned long long it = gedges[own_lo + tid];
    unsigned pid = (unsigned)it;
    unsigned ra = par[pid >> 16];
    unsigned rb = par[pid & 0xffffu];
    hintR[tid] = (ra << 16) | rb;
    hintE[tid] = (unsigned)(it >> 32);
    hintB[tid] = d2b[(ra > rb) ? ra : rb];
  }
  __syncthreads();
  if (tid >= 64) return;
  const int lane = tid;
  if (lane == 0) {
    unsigned nb = 0;
    for (unsigned e = 0; e < mc; ++e) {
      unsigned h = hintR[e];
      unsigned ra = h >> 16, rb = h & 0xffffu;
      if (ra == rb) continue;
      unsigned ca = ra, pa = par[ca];
      while (pa != ca) { unsigned ga = par[pa]; par[ca] = ga; ca = ga; pa = par[ca]; }
      unsigned cb = rb, pb = par[cb];
      while (pb != cb) { unsigned gb = par[pb]; par[cb] = gb; cb = gb; pb = par[cb]; }
      if (ca == cb) continue;
      unsigned win = (ca < cb) ? ca : cb;
      unsigned los = (ca < cb) ? cb : ca;
      float birth = (ca == ra && cb == rb) ? hintB[e] : d2b[los];
      barbuf[nb++] = birth - unmono(hintE[e]);
      par[los] = win;
    }
    nb_sh = nb;
  }
  __asm__ volatile("s_waitcnt lgkmcnt(0)" ::: "memory");
  __builtin_amdgcn_wave_barrier();
  if (lane == 0) base_sh = atomicAdd(&lcnt[p], nb_sh);
  __asm__ volatile("s_waitcnt vmcnt(0) lgkmcnt(0)" ::: "memory");
  __builtin_amdgcn_wave_barrier();
  unsigned nb = nb_sh, base = base_sh;
  for (unsigned i = lane; i < nb; i += 64) {
    unsigned idx = base + i;
    if (idx < LISTCAP) glist[idx] = barbuf[i];
  }
}

// ---------------------------------------------------------------------------
// Kernel 7: per-problem top-20 (wave-shuffle reduction) + fused final mean.
// ---------------------------------------------------------------------------
__global__ __launch_bounds__(256) void topk_k(float* ws, float* out) {
  __shared__ float sl[LISTCAP];
  __shared__ float wval[4];
  __shared__ int   widx[4];
  int p = blockIdx.x, tid = threadIdx.x;
  const float* glist = (const float*)((const char*)ws + OFF_LIST) + (size_t)p * LISTCAP;
  const unsigned* lcnt = (const unsigned*)((const char*)ws + OFF_LCNT);
  unsigned cnt = lcnt[p]; if (cnt > LISTCAP) cnt = LISTCAP;
  for (unsigned i = tid; i < cnt; i += 256) sl[i] = glist[i];
  __syncthreads();
  float acc = 0.f;
  for (int k = 0; k < K_TOP; ++k) {
    float mv = -1.f; int mi = LISTCAP;
    for (unsigned i = tid; i < cnt; i += 256) {
      float v = sl[i];
      if (v > mv) { mv = v; mi = (int)i; }
    }
    // wave-level reduce (no barriers)
    #pragma unroll
    for (int off = 32; off >= 1; off >>= 1) {
      float ov = __shfl_down(mv, off);
      int   oi = __shfl_down(mi, off);
      if (ov > mv || (ov == mv && oi < mi)) { mv = ov; mi = oi; }
    }
    if ((tid & 63) == 0) { wval[tid >> 6] = mv; widx[tid >> 6] = mi; }
    __syncthreads();
    if (tid == 0) {
      float bv = wval[0]; int bi = widx[0];
      #pragma unroll
      for (int w = 1; w < 4; ++w) {
        if (wval[w] > bv || (wval[w] == bv && widx[w] < bi)) { bv = wval[w]; bi = widx[w]; }
      }
      float best = bv > 0.f ? bv : 0.f;
      float sgnk = (k < 5) ? -1.f : 1.f;
      acc += sgnk * best * best;
      if (bi < LISTCAP) sl[bi] = -2.f;
    }
    __syncthreads();
  }
  if (tid == 0) atomicAdd(out, acc * (1.f / (float)NB));
}

extern "C" void kernel_launch(void* const* d_in, const int* in_sizes, int n_in,
                              void* d_out, int out_size, void* d_ws, size_t ws_size,
                              hipStream_t stream) {
  const float* in = (const float*)d_in[0];
  float* ws = (float*)d_ws;
  float* out = (float*)d_out;
  hipLaunchKernelGGL(resize_init_k, dim3(RBLK + NPROB), dim3(256), 0, stream, in, ws, out);
  hipLaunchKernelGGL(spnchase_k, dim3(NPROB), dim3(256), 0, stream, ws);
  hipLaunchKernelGGL(rank_root_k, dim3(NPROB * 16), dim3(256), 0, stream, ws);
  hipLaunchKernelGGL(hash_k, dim3(NPROB * 8), dim3(256), 0, stream, ws);
  hipLaunchKernelGGL(sortcc_k, dim3(NPROB), dim3(256), 0, stream, ws);
  hipLaunchKernelGGL(kruskal_bucket_k, dim3(NPROB * KB), dim3(256), 0, stream, ws);
  hipLaunchKernelGGL(topk_k, dim3(NPROB), dim3(256), 0, stream, ws, out);
}

// Round 15
// 377.435 us; speedup vs baseline: 1.0378x; 1.0378x over previous
//
#include <hip/hip_runtime.h>
#include <math.h>

#define NB 16
#define INW 256
#define GN 100
#define NV (GN*GN)          // 10000
#define NPROB (NB*2)        // 32
#define K_TOP 20
#define HSZ 8192
#define KB 64               // positional buckets per problem
#define SNAPN 8             // snapshots (every 8 buckets)
#define RCAP 3072           // max regions per problem
#define MYCAP 128           // max edges per bucket
#define LISTCAP 3072        // max bars per problem
#define RBLK 625            // resize blocks (NB*NV/256)
#define ST 512              // sortcc block size

// ws layout
#define OFF_RES   0               // NB*NV f32 = 640000
#define OFF_DENSE 1280000         // NPROB*NV u16 (alive until hash_k)
#define OFF_STATE 0               // overlay: NPROB*SNAPN*RCAP u16 (written by sortcc, after hash)
#define OFF_ROOTV 1920000         // NPROB*RCAP u16
#define OFF_D2B   2116608         // NPROB*RCAP f32
#define OFF_TAB   2509824         // NPROB*HSZ u64 (hash table -> sorted edges)
#define OFF_ECNT  4606976         // NPROB u32
#define OFF_RCNT  4607104         // NPROB u32
#define OFF_LCNT  4607232         // NPROB u32
#define OFF_LIST  4607360         // NPROB*LISTCAP f32
#define OFF_PART  5000576         // NPROB f32
#define OFF_FLAB  5000704         // NPROB*NV u16

__device__ __forceinline__ int imin(int a, int b){ return a < b ? a : b; }
__device__ __forceinline__ int imax(int a, int b){ return a > b ? a : b; }

__device__ __forceinline__ unsigned mono32(float f){
  unsigned b = __float_as_uint(f);
  return (b & 0x80000000u) ? ~b : (b | 0x80000000u);
}
__device__ __forceinline__ float unmono(unsigned m){
  unsigned b = (m & 0x80000000u) ? (m ^ 0x80000000u) : ~m;
  return __uint_as_float(b);
}

__device__ __forceinline__ unsigned uf_find(volatile unsigned* par, unsigned x){
  unsigned p = par[x];
  while (p != x) {
    unsigned g = par[p];
    if (g != p) par[x] = g;
    x = g;
    p = par[x];
  }
  return x;
}
__device__ __forceinline__ void uf_union(volatile unsigned* vpar, unsigned* par,
                                         unsigned a, unsigned b){
  while (1) {
    unsigned ra = uf_find(vpar, a);
    unsigned rb = uf_find(vpar, b);
    if (ra == rb) break;
    unsigned lo = (ra < rb) ? ra : rb, hi = (ra < rb) ? rb : ra;
    if (atomicCAS(&par[hi], hi, lo) == hi) break;
    a = lo; b = hi;
  }
}

__device__ __forceinline__ void cub_w(int i, int& j0, float w[4]) {
  double inv = (double)INW / (double)GN;
  double sf  = ((double)i + 0.5) * inv - 0.5;
  j0 = (int)floor(sf) - 1;
  double wd[4]; double s = 0.0;
  #pragma unroll
  for (int k = 0; k < 4; ++k) {
    int j = j0 + k;
    double t = fabs(sf - (double)j);
    double v;
    if (t < 1.0)      v = ((1.5*t - 2.5)*t)*t + 1.0;
    else if (t < 2.0) v = ((-0.5*t + 2.5)*t - 4.0)*t + 2.0;
    else              v = 0.0;
    if (j < 0 || j >= INW) v = 0.0;
    wd[k] = v; s += v;
  }
  #pragma unroll
  for (int k = 0; k < 4; ++k) w[k] = (float)(wd[k] / s);
}

// ---------------------------------------------------------------------------
// Kernel 1: bicubic resize + per-problem init
// ---------------------------------------------------------------------------
__global__ __launch_bounds__(256) void resize_init_k(const float* __restrict__ in,
                                                     float* ws, float* out) {
  int tid = threadIdx.x;
  if (blockIdx.x >= RBLK) {
    int p = blockIdx.x - RBLK;
    unsigned long long* tab = (unsigned long long*)((char*)ws + OFF_TAB) + (size_t)p * HSZ;
    for (int i = tid; i < HSZ; i += 256) tab[i] = 0ull;
    if (tid == 0) {
      ((unsigned*)((char*)ws + OFF_ECNT))[p] = 0u;
      ((unsigned*)((char*)ws + OFF_RCNT))[p] = 0u;
      ((unsigned*)((char*)ws + OFF_LCNT))[p] = 0u;
      if (p == 0) out[0] = 0.f;
    }
    return;
  }
  float* outp = (float*)((char*)ws + OFF_RES);
  int idx = blockIdx.x * 256 + tid;
  if (idx >= NB * NV) return;
  int b = idx / NV; int rem = idx - b * NV;
  int i = rem / GN; int j = rem - i * GN;
  const float* img = in + (size_t)b * INW * INW;
  int r0, c0; float wr[4], wc[4];
  cub_w(i, r0, wr);
  cub_w(j, c0, wc);
  float acc = 0.f;
  #pragma unroll
  for (int kr = 0; kr < 4; ++kr) {
    int rr = imin(imax(r0 + kr, 0), INW - 1);
    const float* row = img + rr * INW;
    int c0c = imin(imax(c0 + 0, 0), INW - 1);
    int c1c = imin(imax(c0 + 1, 0), INW - 1);
    int c2c = imin(imax(c0 + 2, 0), INW - 1);
    int c3c = imin(imax(c0 + 3, 0), INW - 1);
    float rs = wc[0]*row[c0c] + wc[1]*row[c1c] + wc[2]*row[c2c] + wc[3]*row[c3c];
    acc += wr[kr] * rs;
  }
  outp[idx] = acc;
}

// ---------------------------------------------------------------------------
// Kernel 2: FUSED steepest-earlier-neighbor + LDS chase + root compaction
// ---------------------------------------------------------------------------
__global__ __launch_bounds__(256) void spnchase_k(float* ws) {
  __shared__ unsigned sm[NV];
  __shared__ unsigned short lab[NV];
  __shared__ unsigned cnt[256];
  int p = blockIdx.x, tid = threadIdx.x;
  int samp = p >> 1, neg = p & 1;
  const float* res = (const float*)((const char*)ws + OFF_RES) + samp * NV;
  unsigned short* flab = (unsigned short*)((char*)ws + OFF_FLAB) + (size_t)p * NV;
  unsigned short* rootv = (unsigned short*)((char*)ws + OFF_ROOTV) + (size_t)p * RCAP;
  unsigned* rcnt = (unsigned*)((char*)ws + OFF_RCNT);
  float sgn = neg ? -1.f : 1.f;
  for (int i = tid; i < NV; i += 256) sm[i] = mono32(sgn * res[i]);
  __syncthreads();
  const int nd = neg ? 4 : 6;
  for (int v = tid; v < NV; v += 256) {
    int r = v / GN, c = v - r * GN;
    unsigned long long best = ((unsigned long long)sm[v] << 32) | (unsigned)~(unsigned)v;
    unsigned bi = (unsigned)v;
    bool cb[6] = { c < GN-1, c > 0, r < GN-1, r > 0,
                   (r < GN-1) && (c < GN-1), (r > 0) && (c > 0) };
    int  off[6] = { 1, -1, GN, -GN, GN+1, -(GN+1) };
    #pragma unroll
    for (int d = 0; d < 6; ++d) {
      if (d < nd && cb[d]) {
        unsigned y = (unsigned)(v + off[d]);
        unsigned long long o = ((unsigned long long)sm[y] << 32) | (unsigned)~y;
        if (o > best) { best = o; bi = y; }
      }
    }
    lab[v] = (unsigned short)bi;
  }
  __syncthreads();
  for (int v = tid; v < NV; v += 256) {
    unsigned r = lab[v];
    while (1) { unsigned n = lab[r]; if (n == r) break; r = n; }
    lab[v] = (unsigned short)r;
    flab[v] = (unsigned short)r;
  }
  __syncthreads();
  unsigned my = 0;
  for (int v = tid; v < NV; v += 256) if (lab[v] == (unsigned short)v) ++my;
  cnt[tid] = my;
  __syncthreads();
  for (int off = 1; off < 256; off <<= 1) {
    unsigned t = (tid >= off) ? cnt[tid - off] : 0u;
    __syncthreads();
    cnt[tid] += t;
    __syncthreads();
  }
  unsigned base = cnt[tid] - my;
  for (int v = tid; v < NV; v += 256) {
    if (lab[v] == (unsigned short)v) {
      if (base < RCAP) rootv[base] = (unsigned short)v;
      ++base;
    }
  }
  if (tid == 255) rcnt[p] = (cnt[255] > RCAP) ? RCAP : cnt[255];
}

// ---------------------------------------------------------------------------
// Kernel 3: rank roots desc -> dense ids + birth table
// ---------------------------------------------------------------------------
__global__ __launch_bounds__(256) void rank_root_k(float* ws) {
  __shared__ unsigned long long ro[RCAP];
  __shared__ unsigned short rv_sh[RCAP];
  int p = blockIdx.x / 16, sl = blockIdx.x % 16, tid = threadIdx.x;
  int samp = p >> 1, neg = p & 1;
  const float* res = (const float*)((const char*)ws + OFF_RES) + samp * NV;
  const unsigned short* rootv = (const unsigned short*)((const char*)ws + OFF_ROOTV) + (size_t)p * RCAP;
  unsigned short* dense = (unsigned short*)((char*)ws + OFF_DENSE) + (size_t)p * NV;
  float* d2b = (float*)((char*)ws + OFF_D2B) + (size_t)p * RCAP;
  const unsigned* rcnt = (const unsigned*)((const char*)ws + OFF_RCNT);
  unsigned R = rcnt[p]; if (R > RCAP) R = RCAP;
  float sgn = neg ? -1.f : 1.f;
  for (unsigned i = tid; i < R; i += 256) {
    unsigned v = rootv[i];
    ro[i] = ((unsigned long long)mono32(sgn * res[v]) << 32) | (unsigned)~v;
    rv_sh[i] = (unsigned short)v;
  }
  __syncthreads();
  unsigned RS = (R + 15) / 16;
  unsigned lo = sl * RS, hi = lo + RS; if (hi > R) hi = R;
  for (unsigned i = lo + tid; i < hi; i += 256) {
    unsigned long long oi = ro[i];
    unsigned r = 0;
    for (unsigned j = 0; j < R; ++j) r += (ro[j] > oi) ? 1u : 0u;
    dense[rv_sh[i]] = (unsigned short)r;
    d2b[r] = unmono((unsigned)(oi >> 32));
  }
}

// ---------------------------------------------------------------------------
// Kernel 4: boundary-edge dedup into GLOBAL u64 hash table. 8 slices/problem.
// ---------------------------------------------------------------------------
__global__ __launch_bounds__(256) void hash_k(float* ws) {
  int p = blockIdx.x >> 3, sl = blockIdx.x & 7, tid = threadIdx.x;
  int samp = p >> 1, neg = p & 1;
  const float* res = (const float*)((const char*)ws + OFF_RES) + samp * NV;
  const unsigned short* flab = (const unsigned short*)((const char*)ws + OFF_FLAB) + (size_t)p * NV;
  const unsigned short* gdense = (const unsigned short*)((const char*)ws + OFF_DENSE) + (size_t)p * NV;
  unsigned long long* tab = (unsigned long long*)((char*)ws + OFF_TAB) + (size_t)p * HSZ;
  float sgn = neg ? -1.f : 1.f;
  int v0 = sl * (NV / 8), v1 = v0 + (NV / 8);
  for (int v = v0 + tid; v < v1; v += 256) {
    int r = v / GN, c = v - r * GN;
    unsigned a = gdense[flab[v]];
    unsigned sv = mono32(sgn * res[v]);
    bool vb[3] = { c < GN-1, r < GN-1, (!neg) && (r < GN-1) && (c < GN-1) };
    int  vo[3] = { 1, GN, GN+1 };
    #pragma unroll
    for (int d = 0; d < 3; ++d) {
      if (vb[d]) {
        unsigned w = (unsigned)(v + vo[d]);
        unsigned b = gdense[flab[w]];
        if (a != b) {
          unsigned sw = mono32(sgn * res[w]);
          unsigned ev = (sv < sw) ? sv : sw;
          unsigned dlo = (a < b) ? a : b, dhi = (a < b) ? b : a;
          unsigned pid = (dlo << 16) | dhi;
          unsigned long long packed = ((unsigned long long)ev << 32) | pid;
          unsigned h = (pid * 2654435761u) >> 19;
          for (int t = 0; t < HSZ; ++t) {
            unsigned long long cur = tab[h];
            if (cur == 0ull) {
              unsigned long long old = atomicCAS(&tab[h], 0ull, packed);
              if (old == 0ull) break;
              cur = old;
            }
            if ((unsigned)cur == pid) { atomicMax(&tab[h], packed); break; }
            h = (h + 1) & (HSZ - 1);
          }
        }
      }
    }
  }
}

// ---------------------------------------------------------------------------
// Kernel 5: gather + radix sort (desc by ev) + prefix-CC snapshots.
// 512 threads. Register counters + shuffle scans; LDS<->global ping-pong.
// ---------------------------------------------------------------------------
__global__ __launch_bounds__(ST) void sortcc_k(float* ws) {
  __shared__ unsigned long long bufL[HSZ];    // 64KB
  __shared__ unsigned cnt[16 * ST];           // 32KB (scatter bases; par for CC)
  __shared__ unsigned wtot[8 * 16];
  __shared__ unsigned tot[16], stot[16];
  __shared__ unsigned mc_sh;
  __shared__ int skip_sh;
  int p = blockIdx.x, tid = threadIdx.x;
  int wave = tid >> 6, lane = tid & 63;
  unsigned long long* tab = (unsigned long long*)((char*)ws + OFF_TAB) + (size_t)p * HSZ;
  unsigned short* state = (unsigned short*)((char*)ws + OFF_STATE) + (size_t)p * SNAPN * RCAP;
  unsigned* ecnt = (unsigned*)((char*)ws + OFF_ECNT);
  const unsigned* rcnt = (const unsigned*)((const char*)ws + OFF_RCNT);
  unsigned R = rcnt[p]; if (R > RCAP) R = RCAP;
  // ---- gather: TAB -> bufL (deterministic scan compaction) ----
  const int GS = HSZ / ST;                    // 16 slots each
  int g0 = tid * GS;
  unsigned mn = 0;
  for (int i = g0; i < g0 + GS; ++i) mn += (tab[i] != 0ull) ? 1u : 0u;
  unsigned ginc = mn;
  #pragma unroll
  for (int off = 1; off < 64; off <<= 1) {
    unsigned v = __shfl_up(ginc, off);
    if (lane >= off) ginc += v;
  }
  if (lane == 63) wtot[wave] = ginc;
  __syncthreads();
  if (tid == 0) {
    unsigned run = 0;
    for (int w = 0; w < 8; ++w) { unsigned t = wtot[w]; wtot[w] = run; run += t; }
    mc_sh = run;
  }
  __syncthreads();
  {
    unsigned base = wtot[wave] + ginc - mn;
    for (int i = g0; i < g0 + GS; ++i) {
      unsigned long long x = tab[i];
      if (x != 0ull) bufL[base++] = x;
    }
  }
  unsigned E = mc_sh;
  __syncthreads();
  // ---- radix: 8 x 4-bit, desc, stable. src alternates LDS/global ----
  unsigned chunk = (E + ST - 1) / ST;
  unsigned lo = tid * chunk; if (lo > E) lo = E;
  unsigned hi = lo + chunk; if (hi > E) hi = E;
  bool inLds = true;
  for (int pass = 0; pass < 8; ++pass) {
    int shift = 32 + pass * 4;
    unsigned myc[16];
    #pragma unroll
    for (int s = 0; s < 16; ++s) myc[s] = 0;
    for (unsigned i = lo; i < hi; ++i) {
      unsigned long long x = inLds ? bufL[i] : tab[i];
      unsigned slot = 15u - ((unsigned)(x >> shift) & 15u);
      #pragma unroll
      for (int s = 0; s < 16; ++s) myc[s] += (slot == (unsigned)s) ? 1u : 0u;
    }
    unsigned incl[16];
    #pragma unroll
    for (int s = 0; s < 16; ++s) incl[s] = myc[s];
    #pragma unroll
    for (int off = 1; off < 64; off <<= 1) {
      #pragma unroll
      for (int s = 0; s < 16; ++s) {
        unsigned v = __shfl_up(incl[s], off);
        if (lane >= off) incl[s] += v;
      }
    }
    if (lane == 63) {
      #pragma unroll
      for (int s = 0; s < 16; ++s) wtot[wave * 16 + s] = incl[s];
    }
    __syncthreads();
    if (tid < 16) {
      unsigned run = 0;
      for (int w = 0; w < 8; ++w) {
        unsigned t = wtot[w * 16 + tid];
        wtot[w * 16 + tid] = run;
        run += t;
      }
      tot[tid] = run;
    }
    __syncthreads();
    if (tid == 0) {
      int sk = 0; unsigned s_ = 0;
      for (int d = 0; d < 16; ++d) { unsigned c = tot[d]; if (c == E) sk = 1; stot[d] = s_; s_ += c; }
      skip_sh = sk;
    }
    __syncthreads();
    if (skip_sh) continue;                     // all items share this digit
    #pragma unroll
    for (int s = 0; s < 16; ++s)
      cnt[s * ST + tid] = stot[s] + wtot[wave * 16 + s] + incl[s] - myc[s];
    for (unsigned i = lo; i < hi; ++i) {
      unsigned long long x = inLds ? bufL[i] : tab[i];
      unsigned slot = 15u - ((unsigned)(x >> shift) & 15u);
      unsigned a = slot * ST + tid;
      unsigned off = cnt[a]; cnt[a] = off + 1u;
      if (inLds) tab[off] = x; else bufL[off] = x;
    }
    __syncthreads();
    inLds = !inLds;
  }
  // ---- ensure sorted edges in TAB ----
  if (inLds) {
    for (unsigned i = tid; i < E; i += ST) tab[i] = bufL[i];
  }
  if (tid == 0) ecnt[p] = E;
  __syncthreads();
  // ---- prefix-CC snapshots (par reuses cnt region) ----
  unsigned* par = cnt;
  for (unsigned d = tid; d < R; d += ST) par[d] = d;
  __syncthreads();
  volatile unsigned* vpar = par;
  unsigned cp = (E + KB - 1) / KB;
  for (int s = 0; s < SNAPN; ++s) {
    for (unsigned d = tid; d < R; d += ST) {
      unsigned r = d;
      while (vpar[r] != r) r = vpar[r];
      par[d] = r;
      state[s * RCAP + d] = (unsigned short)r;
    }
    __syncthreads();
    unsigned e0 = (unsigned)s * 8u * cp; if (e0 > E) e0 = E;
    unsigned e1 = (unsigned)(s + 1) * 8u * cp; if (e1 > E) e1 = E;
    for (unsigned e = e0 + tid; e < e1; e += ST) {
      unsigned pid = (unsigned)tab[e];
      uf_union(vpar, par, pid >> 16, pid & 0xffffu);
    }
    __syncthreads();
  }
}

// ---------------------------------------------------------------------------
// Kernel 6: bucketed Kruskal with speculative root hints.
// ---------------------------------------------------------------------------
__global__ __launch_bounds__(256) void kruskal_bucket_k(float* ws) {
  __shared__ unsigned par[RCAP];
  __shared__ unsigned hintR[MYCAP];
  __shared__ unsigned hintE[MYCAP];
  __shared__ float    hintB[MYCAP];
  __shared__ float    barbuf[MYCAP];
  __shared__ unsigned nb_sh, base_sh;
  int p = blockIdx.x / KB, bk = blockIdx.x % KB, tid = threadIdx.x;
  const unsigned long long* gedges = (const unsigned long long*)((const char*)ws + OFF_TAB) + (size_t)p * HSZ;
  const float* d2b = (const float*)((const char*)ws + OFF_D2B) + (size_t)p * RCAP;
  const unsigned short* state = (const unsigned short*)((const char*)ws + OFF_STATE) + (size_t)p * SNAPN * RCAP + (size_t)(bk >> 3) * RCAP;
  const unsigned* ecnt = (const unsigned*)((const char*)ws + OFF_ECNT);
  const unsigned* rcnt = (const unsigned*)((const char*)ws + OFF_RCNT);
  unsigned* lcnt = (unsigned*)((char*)ws + OFF_LCNT);
  float* glist = (float*)((char*)ws + OFF_LIST) + (size_t)p * LISTCAP;
  unsigned E = ecnt[p]; if (E > HSZ) E = HSZ;
  unsigned R = rcnt[p]; if (R > RCAP) R = RCAP;
  unsigned cp = (E + KB - 1) / KB;
  unsigned rep_lo = (unsigned)(bk & ~7) * cp; if (rep_lo > E) rep_lo = E;
  unsigned own_lo = (unsigned)bk * cp;        if (own_lo > E) own_lo = E;
  unsigned own_hi = own_lo + cp;              if (own_hi > E) own_hi = E;
  unsigned mc = own_hi - own_lo;
  for (unsigned d = tid; d < R; d += 256) par[d] = state[d];
  __syncthreads();
  volatile unsigned* vpar = par;
  for (unsigned e = rep_lo + tid; e < own_lo; e += 256) {
    unsigned pid = (unsigned)gedges[e];
    uf_union(vpar, par, pid >> 16, pid & 0xffffu);
  }
  __syncthreads();
  for (unsigned d = tid; d < R; d += 256) {
    unsigned r = d;
    while (vpar[r] != r) r = vpar[r];
    par[d] = r;
  }
  __syncthreads();
  if (tid < mc) {
    unsigned long long it = gedges[own_lo + tid];
    unsigned pid = (unsigned)it;
    unsigned ra = par[pid >> 16];
    unsigned rb = par[pid & 0xffffu];
    hintR[tid] = (ra << 16) | rb;
    hintE[tid] = (unsigned)(it >> 32);
    hintB[tid] = d2b[(ra > rb) ? ra : rb];
  }
  __syncthreads();
  if (tid >= 64) return;
  const int lane = tid;
  if (lane == 0) {
    unsigned nb = 0;
    for (unsigned e = 0; e < mc; ++e) {
      unsigned h = hintR[e];
      unsigned ra = h >> 16, rb = h & 0xffffu;
      if (ra == rb) continue;
      unsigned ca = ra, pa = par[ca];
      while (pa != ca) { unsigned ga = par[pa]; par[ca] = ga; ca = ga; pa = par[ca]; }
      unsigned cb = rb, pb = par[cb];
      while (pb != cb) { unsigned gb = par[pb]; par[cb] = gb; cb = gb; pb = par[cb]; }
      if (ca == cb) continue;
      unsigned win = (ca < cb) ? ca : cb;
      unsigned los = (ca < cb) ? cb : ca;
      float birth = (ca == ra && cb == rb) ? hintB[e] : d2b[los];
      barbuf[nb++] = birth - unmono(hintE[e]);
      par[los] = win;
    }
    nb_sh = nb;
  }
  __asm__ volatile("s_waitcnt lgkmcnt(0)" ::: "memory");
  __builtin_amdgcn_wave_barrier();
  if (lane == 0) base_sh = atomicAdd(&lcnt[p], nb_sh);
  __asm__ volatile("s_waitcnt vmcnt(0) lgkmcnt(0)" ::: "memory");
  __builtin_amdgcn_wave_barrier();
  unsigned nb = nb_sh, base = base_sh;
  for (unsigned i = lane; i < nb; i += 64) {
    unsigned idx = base + i;
    if (idx < LISTCAP) glist[idx] = barbuf[i];
  }
}

// ---------------------------------------------------------------------------
// Kernel 7: per-problem top-20 (wave-shuffle reduction) + fused final mean.
// ---------------------------------------------------------------------------
__global__ __launch_bounds__(256) void topk_k(float* ws, float* out) {
  __shared__ float sl[LISTCAP];
  __shared__ float wval[4];
  __shared__ int   widx[4];
  int p = blockIdx.x, tid = threadIdx.x;
  const float* glist = (const float*)((const char*)ws + OFF_LIST) + (size_t)p * LISTCAP;
  const unsigned* lcnt = (const unsigned*)((const char*)ws + OFF_LCNT);
  unsigned cnt = lcnt[p]; if (cnt > LISTCAP) cnt = LISTCAP;
  for (unsigned i = tid; i < cnt; i += 256) sl[i] = glist[i];
  __syncthreads();
  float acc = 0.f;
  for (int k = 0; k < K_TOP; ++k) {
    float mv = -1.f; int mi = LISTCAP;
    for (unsigned i = tid; i < cnt; i += 256) {
      float v = sl[i];
      if (v > mv) { mv = v; mi = (int)i; }
    }
    #pragma unroll
    for (int off = 32; off >= 1; off >>= 1) {
      float ov = __shfl_down(mv, off);
      int   oi = __shfl_down(mi, off);
      if (ov > mv || (ov == mv && oi < mi)) { mv = ov; mi = oi; }
    }
    if ((tid & 63) == 0) { wval[tid >> 6] = mv; widx[tid >> 6] = mi; }
    __syncthreads();
    if (tid == 0) {
      float bv = wval[0]; int bi = widx[0];
      #pragma unroll
      for (int w = 1; w < 4; ++w) {
        if (wval[w] > bv || (wval[w] == bv && widx[w] < bi)) { bv = wval[w]; bi = widx[w]; }
      }
      float best = bv > 0.f ? bv : 0.f;
      float sgnk = (k < 5) ? -1.f : 1.f;
      acc += sgnk * best * best;
      if (bi < LISTCAP) sl[bi] = -2.f;
    }
    __syncthreads();
  }
  if (tid == 0) atomicAdd(out, acc * (1.f / (float)NB));
}

extern "C" void kernel_launch(void* const* d_in, const int* in_sizes, int n_in,
                              void* d_out, int out_size, void* d_ws, size_t ws_size,
                              hipStream_t stream) {
  const float* in = (const float*)d_in[0];
  float* ws = (float*)d_ws;
  float* out = (float*)d_out;
  hipLaunchKernelGGL(resize_init_k, dim3(RBLK + NPROB), dim3(256), 0, stream, in, ws, out);
  hipLaunchKernelGGL(spnchase_k, dim3(NPROB), dim3(256), 0, stream, ws);
  hipLaunchKernelGGL(rank_root_k, dim3(NPROB * 16), dim3(256), 0, stream, ws);
  hipLaunchKernelGGL(hash_k, dim3(NPROB * 8), dim3(256), 0, stream, ws);
  hipLaunchKernelGGL(sortcc_k, dim3(NPROB), dim3(ST), 0, stream, ws);
  hipLaunchKernelGGL(kruskal_bucket_k, dim3(NPROB * KB), dim3(256), 0, stream, ws);
  hipLaunchKernelGGL(topk_k, dim3(NPROB), dim3(256), 0, stream, ws, out);
}

// Round 16
// 348.433 us; speedup vs baseline: 1.1242x; 1.0832x over previous
//
#include <hip/hip_runtime.h>
#include <math.h>

#define NB 16
#define INW 256
#define GN 100
#define NV (GN*GN)          // 10000
#define NPROB (NB*2)        // 32
#define K_TOP 20
#define HSZ 8192
#define KB 64               // positional buckets per problem
#define SNAPN 8             // snapshots (every 8 buckets)
#define RCAP 3072           // max regions per problem
#define MYCAP 128           // max edges per bucket
#define LISTCAP 3072        // max bars per problem
#define RBLK 625            // resize blocks (NB*NV/256)
#define ST 512              // sortcc / spnchase block size

// ws layout
#define OFF_RES   0               // NB*NV f32 = 640000
#define OFF_DENSE 1280000         // NPROB*NV u16 (alive until hash_k)
#define OFF_STATE 0               // overlay: NPROB*SNAPN*RCAP u16 (written by sortcc, after hash)
#define OFF_ROOTV 1920000         // NPROB*RCAP u16
#define OFF_D2B   2116608         // NPROB*RCAP f32
#define OFF_TAB   2509824         // NPROB*HSZ u64 (hash table -> sorted edges)
#define OFF_ECNT  4606976         // NPROB u32
#define OFF_RCNT  4607104         // NPROB u32
#define OFF_LCNT  4607232         // NPROB u32
#define OFF_LIST  4607360         // NPROB*LISTCAP f32
#define OFF_PART  5000576         // NPROB f32
#define OFF_FLAB  5000704         // NPROB*NV u16

__device__ __forceinline__ int imin(int a, int b){ return a < b ? a : b; }
__device__ __forceinline__ int imax(int a, int b){ return a > b ? a : b; }

__device__ __forceinline__ unsigned mono32(float f){
  unsigned b = __float_as_uint(f);
  return (b & 0x80000000u) ? ~b : (b | 0x80000000u);
}
__device__ __forceinline__ float unmono(unsigned m){
  unsigned b = (m & 0x80000000u) ? (m ^ 0x80000000u) : ~m;
  return __uint_as_float(b);
}

__device__ __forceinline__ unsigned uf_find(volatile unsigned* par, unsigned x){
  unsigned p = par[x];
  while (p != x) {
    unsigned g = par[p];
    if (g != p) par[x] = g;
    x = g;
    p = par[x];
  }
  return x;
}
__device__ __forceinline__ void uf_union(volatile unsigned* vpar, unsigned* par,
                                         unsigned a, unsigned b){
  while (1) {
    unsigned ra = uf_find(vpar, a);
    unsigned rb = uf_find(vpar, b);
    if (ra == rb) break;
    unsigned lo = (ra < rb) ? ra : rb, hi = (ra < rb) ? rb : ra;
    if (atomicCAS(&par[hi], hi, lo) == hi) break;
    a = lo; b = hi;
  }
}

__device__ __forceinline__ void cub_w(int i, int& j0, float w[4]) {
  double inv = (double)INW / (double)GN;
  double sf  = ((double)i + 0.5) * inv - 0.5;
  j0 = (int)floor(sf) - 1;
  double wd[4]; double s = 0.0;
  #pragma unroll
  for (int k = 0; k < 4; ++k) {
    int j = j0 + k;
    double t = fabs(sf - (double)j);
    double v;
    if (t < 1.0)      v = ((1.5*t - 2.5)*t)*t + 1.0;
    else if (t < 2.0) v = ((-0.5*t + 2.5)*t - 4.0)*t + 2.0;
    else              v = 0.0;
    if (j < 0 || j >= INW) v = 0.0;
    wd[k] = v; s += v;
  }
  #pragma unroll
  for (int k = 0; k < 4; ++k) w[k] = (float)(wd[k] / s);
}

// ---------------------------------------------------------------------------
// Kernel 1: bicubic resize + per-problem init
// ---------------------------------------------------------------------------
__global__ __launch_bounds__(256) void resize_init_k(const float* __restrict__ in,
                                                     float* ws, float* out) {
  int tid = threadIdx.x;
  if (blockIdx.x >= RBLK) {
    int p = blockIdx.x - RBLK;
    unsigned long long* tab = (unsigned long long*)((char*)ws + OFF_TAB) + (size_t)p * HSZ;
    for (int i = tid; i < HSZ; i += 256) tab[i] = 0ull;
    if (tid == 0) {
      ((unsigned*)((char*)ws + OFF_ECNT))[p] = 0u;
      ((unsigned*)((char*)ws + OFF_RCNT))[p] = 0u;
      ((unsigned*)((char*)ws + OFF_LCNT))[p] = 0u;
      if (p == 0) out[0] = 0.f;
    }
    return;
  }
  float* outp = (float*)((char*)ws + OFF_RES);
  int idx = blockIdx.x * 256 + tid;
  if (idx >= NB * NV) return;
  int b = idx / NV; int rem = idx - b * NV;
  int i = rem / GN; int j = rem - i * GN;
  const float* img = in + (size_t)b * INW * INW;
  int r0, c0; float wr[4], wc[4];
  cub_w(i, r0, wr);
  cub_w(j, c0, wc);
  float acc = 0.f;
  #pragma unroll
  for (int kr = 0; kr < 4; ++kr) {
    int rr = imin(imax(r0 + kr, 0), INW - 1);
    const float* row = img + rr * INW;
    int c0c = imin(imax(c0 + 0, 0), INW - 1);
    int c1c = imin(imax(c0 + 1, 0), INW - 1);
    int c2c = imin(imax(c0 + 2, 0), INW - 1);
    int c3c = imin(imax(c0 + 3, 0), INW - 1);
    float rs = wc[0]*row[c0c] + wc[1]*row[c1c] + wc[2]*row[c2c] + wc[3]*row[c3c];
    acc += wr[kr] * rs;
  }
  outp[idx] = acc;
}

// ---------------------------------------------------------------------------
// Kernel 2: FUSED steepest-earlier-neighbor + LDS chase + root compaction.
// 512 threads (8 waves) for latency hiding; shuffle-scan compaction.
// ---------------------------------------------------------------------------
__global__ __launch_bounds__(ST) void spnchase_k(float* ws) {
  __shared__ unsigned sm[NV];                 // 40KB
  __shared__ unsigned short lab[NV];          // 20KB
  __shared__ unsigned wtot[8];
  __shared__ unsigned Rtot;
  int p = blockIdx.x, tid = threadIdx.x;
  int wave = tid >> 6, lane = tid & 63;
  int samp = p >> 1, neg = p & 1;
  const float* res = (const float*)((const char*)ws + OFF_RES) + samp * NV;
  unsigned short* flab = (unsigned short*)((char*)ws + OFF_FLAB) + (size_t)p * NV;
  unsigned short* rootv = (unsigned short*)((char*)ws + OFF_ROOTV) + (size_t)p * RCAP;
  unsigned* rcnt = (unsigned*)((char*)ws + OFF_RCNT);
  float sgn = neg ? -1.f : 1.f;
  for (int i = tid; i < NV; i += ST) sm[i] = mono32(sgn * res[i]);
  __syncthreads();
  const int nd = neg ? 4 : 6;
  for (int v = tid; v < NV; v += ST) {
    int r = v / GN, c = v - r * GN;
    unsigned long long best = ((unsigned long long)sm[v] << 32) | (unsigned)~(unsigned)v;
    unsigned bi = (unsigned)v;
    bool cb[6] = { c < GN-1, c > 0, r < GN-1, r > 0,
                   (r < GN-1) && (c < GN-1), (r > 0) && (c > 0) };
    int  off[6] = { 1, -1, GN, -GN, GN+1, -(GN+1) };
    #pragma unroll
    for (int d = 0; d < 6; ++d) {
      if (d < nd && cb[d]) {
        unsigned y = (unsigned)(v + off[d]);
        unsigned long long o = ((unsigned long long)sm[y] << 32) | (unsigned)~y;
        if (o > best) { best = o; bi = y; }
      }
    }
    lab[v] = (unsigned short)bi;
  }
  __syncthreads();
  for (int v = tid; v < NV; v += ST) {
    unsigned r = lab[v];
    while (1) { unsigned n = lab[r]; if (n == r) break; r = n; }
    lab[v] = (unsigned short)r;
    flab[v] = (unsigned short)r;
  }
  __syncthreads();
  // shuffle-scan root compaction
  unsigned my = 0;
  for (int v = tid; v < NV; v += ST) if (lab[v] == (unsigned short)v) ++my;
  unsigned incl = my;
  #pragma unroll
  for (int off = 1; off < 64; off <<= 1) {
    unsigned t = __shfl_up(incl, off);
    if (lane >= off) incl += t;
  }
  if (lane == 63) wtot[wave] = incl;
  __syncthreads();
  if (tid == 0) {
    unsigned run = 0;
    for (int w = 0; w < 8; ++w) { unsigned t = wtot[w]; wtot[w] = run; run += t; }
    Rtot = run;
  }
  __syncthreads();
  unsigned base = wtot[wave] + incl - my;
  for (int v = tid; v < NV; v += ST) {
    if (lab[v] == (unsigned short)v) {
      if (base < RCAP) rootv[base] = (unsigned short)v;
      ++base;
    }
  }
  if (tid == 0) rcnt[p] = (Rtot > RCAP) ? RCAP : Rtot;
}

// ---------------------------------------------------------------------------
// Kernel 3: rank roots desc -> dense ids + birth table
// ---------------------------------------------------------------------------
__global__ __launch_bounds__(256) void rank_root_k(float* ws) {
  __shared__ unsigned long long ro[RCAP];
  __shared__ unsigned short rv_sh[RCAP];
  int p = blockIdx.x / 16, sl = blockIdx.x % 16, tid = threadIdx.x;
  int samp = p >> 1, neg = p & 1;
  const float* res = (const float*)((const char*)ws + OFF_RES) + samp * NV;
  const unsigned short* rootv = (const unsigned short*)((const char*)ws + OFF_ROOTV) + (size_t)p * RCAP;
  unsigned short* dense = (unsigned short*)((char*)ws + OFF_DENSE) + (size_t)p * NV;
  float* d2b = (float*)((char*)ws + OFF_D2B) + (size_t)p * RCAP;
  const unsigned* rcnt = (const unsigned*)((const char*)ws + OFF_RCNT);
  unsigned R = rcnt[p]; if (R > RCAP) R = RCAP;
  float sgn = neg ? -1.f : 1.f;
  for (unsigned i = tid; i < R; i += 256) {
    unsigned v = rootv[i];
    ro[i] = ((unsigned long long)mono32(sgn * res[v]) << 32) | (unsigned)~v;
    rv_sh[i] = (unsigned short)v;
  }
  __syncthreads();
  unsigned RS = (R + 15) / 16;
  unsigned lo = sl * RS, hi = lo + RS; if (hi > R) hi = R;
  for (unsigned i = lo + tid; i < hi; i += 256) {
    unsigned long long oi = ro[i];
    unsigned r = 0;
    for (unsigned j = 0; j < R; ++j) r += (ro[j] > oi) ? 1u : 0u;
    dense[rv_sh[i]] = (unsigned short)r;
    d2b[r] = unmono((unsigned)(oi >> 32));
  }
}

// ---------------------------------------------------------------------------
// Kernel 4: boundary-edge dedup into GLOBAL u64 hash table. 8 slices/problem.
// ---------------------------------------------------------------------------
__global__ __launch_bounds__(256) void hash_k(float* ws) {
  int p = blockIdx.x >> 3, sl = blockIdx.x & 7, tid = threadIdx.x;
  int samp = p >> 1, neg = p & 1;
  const float* res = (const float*)((const char*)ws + OFF_RES) + samp * NV;
  const unsigned short* flab = (const unsigned short*)((const char*)ws + OFF_FLAB) + (size_t)p * NV;
  const unsigned short* gdense = (const unsigned short*)((const char*)ws + OFF_DENSE) + (size_t)p * NV;
  unsigned long long* tab = (unsigned long long*)((char*)ws + OFF_TAB) + (size_t)p * HSZ;
  float sgn = neg ? -1.f : 1.f;
  int v0 = sl * (NV / 8), v1 = v0 + (NV / 8);
  for (int v = v0 + tid; v < v1; v += 256) {
    int r = v / GN, c = v - r * GN;
    unsigned a = gdense[flab[v]];
    unsigned sv = mono32(sgn * res[v]);
    bool vb[3] = { c < GN-1, r < GN-1, (!neg) && (r < GN-1) && (c < GN-1) };
    int  vo[3] = { 1, GN, GN+1 };
    #pragma unroll
    for (int d = 0; d < 3; ++d) {
      if (vb[d]) {
        unsigned w = (unsigned)(v + vo[d]);
        unsigned b = gdense[flab[w]];
        if (a != b) {
          unsigned sw = mono32(sgn * res[w]);
          unsigned ev = (sv < sw) ? sv : sw;
          unsigned dlo = (a < b) ? a : b, dhi = (a < b) ? b : a;
          unsigned pid = (dlo << 16) | dhi;
          unsigned long long packed = ((unsigned long long)ev << 32) | pid;
          unsigned h = (pid * 2654435761u) >> 19;
          for (int t = 0; t < HSZ; ++t) {
            unsigned long long cur = tab[h];
            if (cur == 0ull) {
              unsigned long long old = atomicCAS(&tab[h], 0ull, packed);
              if (old == 0ull) break;
              cur = old;
            }
            if ((unsigned)cur == pid) { atomicMax(&tab[h], packed); break; }
            h = (h + 1) & (HSZ - 1);
          }
        }
      }
    }
  }
}

// ---------------------------------------------------------------------------
// Kernel 5: gather + ALL-LDS radix sort (desc by ev, split key/pay u32
// arrays, u16 scatter bases) + prefix-CC snapshots (pids read from LDS).
// 512 threads. Only global ops: gather-in + one writeback + snapshots.
// ---------------------------------------------------------------------------
__global__ __launch_bounds__(ST) void sortcc_k(float* ws) {
  __shared__ unsigned keyA[HSZ], payA[HSZ];   // 64KB
  __shared__ unsigned keyB[HSZ], payB[HSZ];   // 64KB
  __shared__ unsigned short cofs[16 * ST];    // 16KB
  __shared__ unsigned wtot[8 * 16];
  __shared__ unsigned tot[16], stot[16];
  __shared__ unsigned mc_sh;
  __shared__ int skip_sh;
  int p = blockIdx.x, tid = threadIdx.x;
  int wave = tid >> 6, lane = tid & 63;
  unsigned long long* tab = (unsigned long long*)((char*)ws + OFF_TAB) + (size_t)p * HSZ;
  unsigned short* state = (unsigned short*)((char*)ws + OFF_STATE) + (size_t)p * SNAPN * RCAP;
  unsigned* ecnt = (unsigned*)((char*)ws + OFF_ECNT);
  const unsigned* rcnt = (const unsigned*)((const char*)ws + OFF_RCNT);
  unsigned R = rcnt[p]; if (R > RCAP) R = RCAP;
  // ---- gather: TAB -> keyA/payA (deterministic scan compaction) ----
  const int GS = HSZ / ST;                    // 16 slots each
  int g0 = tid * GS;
  unsigned mn = 0;
  for (int i = g0; i < g0 + GS; ++i) mn += (tab[i] != 0ull) ? 1u : 0u;
  unsigned ginc = mn;
  #pragma unroll
  for (int off = 1; off < 64; off <<= 1) {
    unsigned v = __shfl_up(ginc, off);
    if (lane >= off) ginc += v;
  }
  if (lane == 63) wtot[wave] = ginc;
  __syncthreads();
  if (tid == 0) {
    unsigned run = 0;
    for (int w = 0; w < 8; ++w) { unsigned t = wtot[w]; wtot[w] = run; run += t; }
    mc_sh = run;
  }
  __syncthreads();
  {
    unsigned base = wtot[wave] + ginc - mn;
    for (int i = g0; i < g0 + GS; ++i) {
      unsigned long long x = tab[i];
      if (x != 0ull) { keyA[base] = (unsigned)(x >> 32); payA[base] = (unsigned)x; ++base; }
    }
  }
  unsigned E = mc_sh;
  __syncthreads();
  // ---- radix: 8 x 4-bit on 32-bit ev, desc, stable, all-LDS ping-pong ----
  unsigned chunk = (E + ST - 1) / ST;
  unsigned lo = tid * chunk; if (lo > E) lo = E;
  unsigned hi = lo + chunk; if (hi > E) hi = E;
  bool srcA = true;
  for (int pass = 0; pass < 8; ++pass) {
    int shift = pass * 4;
    const unsigned* sk = srcA ? keyA : keyB;
    const unsigned* sp = srcA ? payA : payB;
    unsigned* dk = srcA ? keyB : keyA;
    unsigned* dp = srcA ? payB : payA;
    unsigned myc[16];
    #pragma unroll
    for (int s = 0; s < 16; ++s) myc[s] = 0;
    for (unsigned i = lo; i < hi; ++i) {
      unsigned slot = 15u - ((sk[i] >> shift) & 15u);
      #pragma unroll
      for (int s = 0; s < 16; ++s) myc[s] += (slot == (unsigned)s) ? 1u : 0u;
    }
    unsigned incl[16];
    #pragma unroll
    for (int s = 0; s < 16; ++s) incl[s] = myc[s];
    #pragma unroll
    for (int off = 1; off < 64; off <<= 1) {
      #pragma unroll
      for (int s = 0; s < 16; ++s) {
        unsigned v = __shfl_up(incl[s], off);
        if (lane >= off) incl[s] += v;
      }
    }
    if (lane == 63) {
      #pragma unroll
      for (int s = 0; s < 16; ++s) wtot[wave * 16 + s] = incl[s];
    }
    __syncthreads();
    if (tid < 16) {
      unsigned run = 0;
      for (int w = 0; w < 8; ++w) {
        unsigned t = wtot[w * 16 + tid];
        wtot[w * 16 + tid] = run;
        run += t;
      }
      tot[tid] = run;
    }
    __syncthreads();
    if (tid == 0) {
      int sk2 = 0; unsigned s_ = 0;
      for (int d = 0; d < 16; ++d) { unsigned c = tot[d]; if (c == E) sk2 = 1; stot[d] = s_; s_ += c; }
      skip_sh = sk2;
    }
    __syncthreads();
    if (skip_sh) continue;                     // all items share this digit
    #pragma unroll
    for (int s = 0; s < 16; ++s)
      cofs[s * ST + tid] = (unsigned short)(stot[s] + wtot[wave * 16 + s] + incl[s] - myc[s]);
    for (unsigned i = lo; i < hi; ++i) {
      unsigned k = sk[i];
      unsigned slot = 15u - ((k >> shift) & 15u);
      unsigned a = slot * ST + tid;
      unsigned off = cofs[a]; cofs[a] = (unsigned short)(off + 1u);
      dk[off] = k; dp[off] = sp[i];
    }
    __syncthreads();
    srcA = !srcA;
  }
  const unsigned* fk = srcA ? keyA : keyB;
  const unsigned* fp = srcA ? payA : payB;
  for (unsigned i = tid; i < E; i += ST)
    tab[i] = ((unsigned long long)fk[i] << 32) | fp[i];
  if (tid == 0) ecnt[p] = E;
  __syncthreads();
  // ---- prefix-CC snapshots; par lives in the dead key buffer, pids from LDS ----
  unsigned* par = srcA ? keyB : keyA;
  for (unsigned d = tid; d < R; d += ST) par[d] = d;
  __syncthreads();
  volatile unsigned* vpar = par;
  unsigned cp = (E + KB - 1) / KB;
  for (int s = 0; s < SNAPN; ++s) {
    for (unsigned d = tid; d < R; d += ST) {
      unsigned r = d;
      while (vpar[r] != r) r = vpar[r];
      par[d] = r;
      state[s * RCAP + d] = (unsigned short)r;
    }
    __syncthreads();
    unsigned e0 = (unsigned)s * 8u * cp; if (e0 > E) e0 = E;
    unsigned e1 = (unsigned)(s + 1) * 8u * cp; if (e1 > E) e1 = E;
    for (unsigned e = e0 + tid; e < e1; e += ST) {
      unsigned pid = fp[e];
      uf_union(vpar, par, pid >> 16, pid & 0xffffu);
    }
    __syncthreads();
  }
}

// ---------------------------------------------------------------------------
// Kernel 6: bucketed Kruskal with speculative root hints.
// ---------------------------------------------------------------------------
__global__ __launch_bounds__(256) void kruskal_bucket_k(float* ws) {
  __shared__ unsigned par[RCAP];
  __shared__ unsigned hintR[MYCAP];
  __shared__ unsigned hintE[MYCAP];
  __shared__ float    hintB[MYCAP];
  __shared__ float    barbuf[MYCAP];
  __shared__ unsigned nb_sh, base_sh;
  int p = blockIdx.x / KB, bk = blockIdx.x % KB, tid = threadIdx.x;
  const unsigned long long* gedges = (const unsigned long long*)((const char*)ws + OFF_TAB) + (size_t)p * HSZ;
  const float* d2b = (const float*)((const char*)ws + OFF_D2B) + (size_t)p * RCAP;
  const unsigned short* state = (const unsigned short*)((const char*)ws + OFF_STATE) + (size_t)p * SNAPN * RCAP + (size_t)(bk >> 3) * RCAP;
  const unsigned* ecnt = (const unsigned*)((const char*)ws + OFF_ECNT);
  const unsigned* rcnt = (const unsigned*)((const char*)ws + OFF_RCNT);
  unsigned* lcnt = (unsigned*)((char*)ws + OFF_LCNT);
  float* glist = (float*)((char*)ws + OFF_LIST) + (size_t)p * LISTCAP;
  unsigned E = ecnt[p]; if (E > HSZ) E = HSZ;
  unsigned R = rcnt[p]; if (R > RCAP) R = RCAP;
  unsigned cp = (E + KB - 1) / KB;
  unsigned rep_lo = (unsigned)(bk & ~7) * cp; if (rep_lo > E) rep_lo = E;
  unsigned own_lo = (unsigned)bk * cp;        if (own_lo > E) own_lo = E;
  unsigned own_hi = own_lo + cp;              if (own_hi > E) own_hi = E;
  unsigned mc = own_hi - own_lo;
  for (unsigned d = tid; d < R; d += 256) par[d] = state[d];
  __syncthreads();
  volatile unsigned* vpar = par;
  for (unsigned e = rep_lo + tid; e < own_lo; e += 256) {
    unsigned pid = (unsigned)gedges[e];
    uf_union(vpar, par, pid >> 16, pid & 0xffffu);
  }
  __syncthreads();
  for (unsigned d = tid; d < R; d += 256) {
    unsigned r = d;
    while (vpar[r] != r) r = vpar[r];
    par[d] = r;
  }
  __syncthreads();
  if (tid < mc) {
    unsigned long long it = gedges[own_lo + tid];
    unsigned pid = (unsigned)it;
    unsigned ra = par[pid >> 16];
    unsigned rb = par[pid & 0xffffu];
    hintR[tid] = (ra << 16) | rb;
    hintE[tid] = (unsigned)(it >> 32);
    hintB[tid] = d2b[(ra > rb) ? ra : rb];
  }
  __syncthreads();
  if (tid >= 64) return;
  const int lane = tid;
  if (lane == 0) {
    unsigned nb = 0;
    for (unsigned e = 0; e < mc; ++e) {
      unsigned h = hintR[e];
      unsigned ra = h >> 16, rb = h & 0xffffu;
      if (ra == rb) continue;
      unsigned ca = ra, pa = par[ca];
      while (pa != ca) { unsigned ga = par[pa]; par[ca] = ga; ca = ga; pa = par[ca]; }
      unsigned cb = rb, pb = par[cb];
      while (pb != cb) { unsigned gb = par[pb]; par[cb] = gb; cb = gb; pb = par[cb]; }
      if (ca == cb) continue;
      unsigned win = (ca < cb) ? ca : cb;
      unsigned los = (ca < cb) ? cb : ca;
      float birth = (ca == ra && cb == rb) ? hintB[e] : d2b[los];
      barbuf[nb++] = birth - unmono(hintE[e]);
      par[los] = win;
    }
    nb_sh = nb;
  }
  __asm__ volatile("s_waitcnt lgkmcnt(0)" ::: "memory");
  __builtin_amdgcn_wave_barrier();
  if (lane == 0) base_sh = atomicAdd(&lcnt[p], nb_sh);
  __asm__ volatile("s_waitcnt vmcnt(0) lgkmcnt(0)" ::: "memory");
  __builtin_amdgcn_wave_barrier();
  unsigned nb = nb_sh, base = base_sh;
  for (unsigned i = lane; i < nb; i += 64) {
    unsigned idx = base + i;
    if (idx < LISTCAP) glist[idx] = barbuf[i];
  }
}

// ---------------------------------------------------------------------------
// Kernel 7: per-problem top-20 (wave-shuffle reduction) + fused final mean.
// ---------------------------------------------------------------------------
__global__ __launch_bounds__(256) void topk_k(float* ws, float* out) {
  __shared__ float sl[LISTCAP];
  __shared__ float wval[4];
  __shared__ int   widx[4];
  int p = blockIdx.x, tid = threadIdx.x;
  const float* glist = (const float*)((const char*)ws + OFF_LIST) + (size_t)p * LISTCAP;
  const unsigned* lcnt = (const unsigned*)((const char*)ws + OFF_LCNT);
  unsigned cnt = lcnt[p]; if (cnt > LISTCAP) cnt = LISTCAP;
  for (unsigned i = tid; i < cnt; i += 256) sl[i] = glist[i];
  __syncthreads();
  float acc = 0.f;
  for (int k = 0; k < K_TOP; ++k) {
    float mv = -1.f; int mi = LISTCAP;
    for (unsigned i = tid; i < cnt; i += 256) {
      float v = sl[i];
      if (v > mv) { mv = v; mi = (int)i; }
    }
    #pragma unroll
    for (int off = 32; off >= 1; off >>= 1) {
      float ov = __shfl_down(mv, off);
      int   oi = __shfl_down(mi, off);
      if (ov > mv || (ov == mv && oi < mi)) { mv = ov; mi = oi; }
    }
    if ((tid & 63) == 0) { wval[tid >> 6] = mv; widx[tid >> 6] = mi; }
    __syncthreads();
    if (tid == 0) {
      float bv = wval[0]; int bi = widx[0];
      #pragma unroll
      for (int w = 1; w < 4; ++w) {
        if (wval[w] > bv || (wval[w] == bv && widx[w] < bi)) { bv = wval[w]; bi = widx[w]; }
      }
      float best = bv > 0.f ? bv : 0.f;
      float sgnk = (k < 5) ? -1.f : 1.f;
      acc += sgnk * best * best;
      if (bi < LISTCAP) sl[bi] = -2.f;
    }
    __syncthreads();
  }
  if (tid == 0) atomicAdd(out, acc * (1.f / (float)NB));
}

extern "C" void kernel_launch(void* const* d_in, const int* in_sizes, int n_in,
                              void* d_out, int out_size, void* d_ws, size_t ws_size,
                              hipStream_t stream) {
  const float* in = (const float*)d_in[0];
  float* ws = (float*)d_ws;
  float* out = (float*)d_out;
  hipLaunchKernelGGL(resize_init_k, dim3(RBLK + NPROB), dim3(256), 0, stream, in, ws, out);
  hipLaunchKernelGGL(spnchase_k, dim3(NPROB), dim3(ST), 0, stream, ws);
  hipLaunchKernelGGL(rank_root_k, dim3(NPROB * 16), dim3(256), 0, stream, ws);
  hipLaunchKernelGGL(hash_k, dim3(NPROB * 8), dim3(256), 0, stream, ws);
  hipLaunchKernelGGL(sortcc_k, dim3(NPROB), dim3(ST), 0, stream, ws);
  hipLaunchKernelGGL(kruskal_bucket_k, dim3(NPROB * KB), dim3(256), 0, stream, ws);
  hipLaunchKernelGGL(topk_k, dim3(NPROB), dim3(256), 0, stream, ws, out);
}

// Round 17
// 322.002 us; speedup vs baseline: 1.2165x; 1.0821x over previous
//
#include <hip/hip_runtime.h>
#include <math.h>

#define NB 16
#define INW 256
#define GN 100
#define NV (GN*GN)          // 10000
#define NPROB (NB*2)        // 32
#define K_TOP 20
#define HSZ 8192
#define HHALF 4096
#define KB 64               // positional buckets per problem
#define SNAPN 8             // snapshots (every 8 buckets)
#define RCAP 3072           // max regions per problem
#define MYCAP 128           // max edges per bucket
#define LISTCAP 3072        // max bars per problem
#define RBLK 625            // resize blocks (NB*NV/256)
#define ST 512              // big-block size

// ws layout
#define OFF_RES   0               // NB*NV f32 = 640000
#define OFF_DENSE 1280000         // NPROB*NV u16 (alive until hash_k)
#define OFF_STATE 0               // overlay: NPROB*SNAPN*RCAP u16 (written after hash)
#define OFF_ROOTV 1920000         // NPROB*RCAP u16
#define OFF_D2B   2116608         // NPROB*RCAP f32
#define OFF_TAB   2509824         // NPROB*HSZ u64 (hash table -> runs -> sorted edges)
#define OFF_ECNT  4606976         // NPROB u32
#define OFF_RCNT  4607104         // NPROB u32
#define OFF_LCNT  4607232         // NPROB u32
#define OFF_LIST  4607360         // NPROB*LISTCAP f32
#define OFF_PART  5000576         // NPROB f32
#define OFF_FLAB  5000704         // NPROB*NV u16
#define OFF_C2    5640704         // NPROB*2 u32 (run sizes)

__device__ __forceinline__ int imin(int a, int b){ return a < b ? a : b; }
__device__ __forceinline__ int imax(int a, int b){ return a > b ? a : b; }

__device__ __forceinline__ unsigned mono32(float f){
  unsigned b = __float_as_uint(f);
  return (b & 0x80000000u) ? ~b : (b | 0x80000000u);
}
__device__ __forceinline__ float unmono(unsigned m){
  unsigned b = (m & 0x80000000u) ? (m ^ 0x80000000u) : ~m;
  return __uint_as_float(b);
}

__device__ __forceinline__ unsigned uf_find(volatile unsigned* par, unsigned x){
  unsigned p = par[x];
  while (p != x) {
    unsigned g = par[p];
    if (g != p) par[x] = g;
    x = g;
    p = par[x];
  }
  return x;
}
__device__ __forceinline__ void uf_union(volatile unsigned* vpar, unsigned* par,
                                         unsigned a, unsigned b){
  while (1) {
    unsigned ra = uf_find(vpar, a);
    unsigned rb = uf_find(vpar, b);
    if (ra == rb) break;
    unsigned lo = (ra < rb) ? ra : rb, hi = (ra < rb) ? rb : ra;
    if (atomicCAS(&par[hi], hi, lo) == hi) break;
    a = lo; b = hi;
  }
}

__device__ __forceinline__ void cub_w(int i, int& j0, float w[4]) {
  double inv = (double)INW / (double)GN;
  double sf  = ((double)i + 0.5) * inv - 0.5;
  j0 = (int)floor(sf) - 1;
  double wd[4]; double s = 0.0;
  #pragma unroll
  for (int k = 0; k < 4; ++k) {
    int j = j0 + k;
    double t = fabs(sf - (double)j);
    double v;
    if (t < 1.0)      v = ((1.5*t - 2.5)*t)*t + 1.0;
    else if (t < 2.0) v = ((-0.5*t + 2.5)*t - 4.0)*t + 2.0;
    else              v = 0.0;
    if (j < 0 || j >= INW) v = 0.0;
    wd[k] = v; s += v;
  }
  #pragma unroll
  for (int k = 0; k < 4; ++k) w[k] = (float)(wd[k] / s);
}

// ---------------------------------------------------------------------------
// Kernel 1: bicubic resize + per-problem init
// ---------------------------------------------------------------------------
__global__ __launch_bounds__(256) void resize_init_k(const float* __restrict__ in,
                                                     float* ws, float* out) {
  int tid = threadIdx.x;
  if (blockIdx.x >= RBLK) {
    int p = blockIdx.x - RBLK;
    unsigned long long* tab = (unsigned long long*)((char*)ws + OFF_TAB) + (size_t)p * HSZ;
    for (int i = tid; i < HSZ; i += 256) tab[i] = 0ull;
    if (tid == 0) {
      ((unsigned*)((char*)ws + OFF_ECNT))[p] = 0u;
      ((unsigned*)((char*)ws + OFF_RCNT))[p] = 0u;
      ((unsigned*)((char*)ws + OFF_LCNT))[p] = 0u;
      if (p == 0) out[0] = 0.f;
    }
    return;
  }
  float* outp = (float*)((char*)ws + OFF_RES);
  int idx = blockIdx.x * 256 + tid;
  if (idx >= NB * NV) return;
  int b = idx / NV; int rem = idx - b * NV;
  int i = rem / GN; int j = rem - i * GN;
  const float* img = in + (size_t)b * INW * INW;
  int r0, c0; float wr[4], wc[4];
  cub_w(i, r0, wr);
  cub_w(j, c0, wc);
  float acc = 0.f;
  #pragma unroll
  for (int kr = 0; kr < 4; ++kr) {
    int rr = imin(imax(r0 + kr, 0), INW - 1);
    const float* row = img + rr * INW;
    int c0c = imin(imax(c0 + 0, 0), INW - 1);
    int c1c = imin(imax(c0 + 1, 0), INW - 1);
    int c2c = imin(imax(c0 + 2, 0), INW - 1);
    int c3c = imin(imax(c0 + 3, 0), INW - 1);
    float rs = wc[0]*row[c0c] + wc[1]*row[c1c] + wc[2]*row[c2c] + wc[3]*row[c3c];
    acc += wr[kr] * rs;
  }
  outp[idx] = acc;
}

// ---------------------------------------------------------------------------
// Kernel 2: FUSED steepest-earlier-neighbor + LDS chase + root compaction.
// ---------------------------------------------------------------------------
__global__ __launch_bounds__(ST) void spnchase_k(float* ws) {
  __shared__ unsigned sm[NV];
  __shared__ unsigned short lab[NV];
  __shared__ unsigned wtot[8];
  __shared__ unsigned Rtot;
  int p = blockIdx.x, tid = threadIdx.x;
  int wave = tid >> 6, lane = tid & 63;
  int samp = p >> 1, neg = p & 1;
  const float* res = (const float*)((const char*)ws + OFF_RES) + samp * NV;
  unsigned short* flab = (unsigned short*)((char*)ws + OFF_FLAB) + (size_t)p * NV;
  unsigned short* rootv = (unsigned short*)((char*)ws + OFF_ROOTV) + (size_t)p * RCAP;
  unsigned* rcnt = (unsigned*)((char*)ws + OFF_RCNT);
  float sgn = neg ? -1.f : 1.f;
  for (int i = tid; i < NV; i += ST) sm[i] = mono32(sgn * res[i]);
  __syncthreads();
  const int nd = neg ? 4 : 6;
  for (int v = tid; v < NV; v += ST) {
    int r = v / GN, c = v - r * GN;
    unsigned long long best = ((unsigned long long)sm[v] << 32) | (unsigned)~(unsigned)v;
    unsigned bi = (unsigned)v;
    bool cb[6] = { c < GN-1, c > 0, r < GN-1, r > 0,
                   (r < GN-1) && (c < GN-1), (r > 0) && (c > 0) };
    int  off[6] = { 1, -1, GN, -GN, GN+1, -(GN+1) };
    #pragma unroll
    for (int d = 0; d < 6; ++d) {
      if (d < nd && cb[d]) {
        unsigned y = (unsigned)(v + off[d]);
        unsigned long long o = ((unsigned long long)sm[y] << 32) | (unsigned)~y;
        if (o > best) { best = o; bi = y; }
      }
    }
    lab[v] = (unsigned short)bi;
  }
  __syncthreads();
  for (int v = tid; v < NV; v += ST) {
    unsigned r = lab[v];
    while (1) { unsigned n = lab[r]; if (n == r) break; r = n; }
    lab[v] = (unsigned short)r;
    flab[v] = (unsigned short)r;
  }
  __syncthreads();
  unsigned my = 0;
  for (int v = tid; v < NV; v += ST) if (lab[v] == (unsigned short)v) ++my;
  unsigned incl = my;
  #pragma unroll
  for (int off = 1; off < 64; off <<= 1) {
    unsigned t = __shfl_up(incl, off);
    if (lane >= off) incl += t;
  }
  if (lane == 63) wtot[wave] = incl;
  __syncthreads();
  if (tid == 0) {
    unsigned run = 0;
    for (int w = 0; w < 8; ++w) { unsigned t = wtot[w]; wtot[w] = run; run += t; }
    Rtot = run;
  }
  __syncthreads();
  unsigned base = wtot[wave] + incl - my;
  for (int v = tid; v < NV; v += ST) {
    if (lab[v] == (unsigned short)v) {
      if (base < RCAP) rootv[base] = (unsigned short)v;
      ++base;
    }
  }
  if (tid == 0) rcnt[p] = (Rtot > RCAP) ? RCAP : Rtot;
}

// ---------------------------------------------------------------------------
// Kernel 3: rank roots desc -> dense ids + birth table
// ---------------------------------------------------------------------------
__global__ __launch_bounds__(256) void rank_root_k(float* ws) {
  __shared__ unsigned long long ro[RCAP];
  __shared__ unsigned short rv_sh[RCAP];
  int p = blockIdx.x / 16, sl = blockIdx.x % 16, tid = threadIdx.x;
  int samp = p >> 1, neg = p & 1;
  const float* res = (const float*)((const char*)ws + OFF_RES) + samp * NV;
  const unsigned short* rootv = (const unsigned short*)((const char*)ws + OFF_ROOTV) + (size_t)p * RCAP;
  unsigned short* dense = (unsigned short*)((char*)ws + OFF_DENSE) + (size_t)p * NV;
  float* d2b = (float*)((char*)ws + OFF_D2B) + (size_t)p * RCAP;
  const unsigned* rcnt = (const unsigned*)((const char*)ws + OFF_RCNT);
  unsigned R = rcnt[p]; if (R > RCAP) R = RCAP;
  float sgn = neg ? -1.f : 1.f;
  for (unsigned i = tid; i < R; i += 256) {
    unsigned v = rootv[i];
    ro[i] = ((unsigned long long)mono32(sgn * res[v]) << 32) | (unsigned)~v;
    rv_sh[i] = (unsigned short)v;
  }
  __syncthreads();
  unsigned RS = (R + 15) / 16;
  unsigned lo = sl * RS, hi = lo + RS; if (hi > R) hi = R;
  for (unsigned i = lo + tid; i < hi; i += 256) {
    unsigned long long oi = ro[i];
    unsigned r = 0;
    for (unsigned j = 0; j < R; ++j) r += (ro[j] > oi) ? 1u : 0u;
    dense[rv_sh[i]] = (unsigned short)r;
    d2b[r] = unmono((unsigned)(oi >> 32));
  }
}

// ---------------------------------------------------------------------------
// Kernel 4: boundary-edge dedup into GLOBAL u64 hash table. 16 slices/problem.
// ---------------------------------------------------------------------------
__global__ __launch_bounds__(256) void hash_k(float* ws) {
  int p = blockIdx.x >> 4, sl = blockIdx.x & 15, tid = threadIdx.x;
  int samp = p >> 1, neg = p & 1;
  const float* res = (const float*)((const char*)ws + OFF_RES) + samp * NV;
  const unsigned short* flab = (const unsigned short*)((const char*)ws + OFF_FLAB) + (size_t)p * NV;
  const unsigned short* gdense = (const unsigned short*)((const char*)ws + OFF_DENSE) + (size_t)p * NV;
  unsigned long long* tab = (unsigned long long*)((char*)ws + OFF_TAB) + (size_t)p * HSZ;
  float sgn = neg ? -1.f : 1.f;
  int v0 = sl * (NV / 16), v1 = v0 + (NV / 16);
  for (int v = v0 + tid; v < v1; v += 256) {
    int r = v / GN, c = v - r * GN;
    unsigned a = gdense[flab[v]];
    unsigned sv = mono32(sgn * res[v]);
    bool vb[3] = { c < GN-1, r < GN-1, (!neg) && (r < GN-1) && (c < GN-1) };
    int  vo[3] = { 1, GN, GN+1 };
    #pragma unroll
    for (int d = 0; d < 3; ++d) {
      if (vb[d]) {
        unsigned w = (unsigned)(v + vo[d]);
        unsigned b = gdense[flab[w]];
        if (a != b) {
          unsigned sw = mono32(sgn * res[w]);
          unsigned ev = (sv < sw) ? sv : sw;
          unsigned dlo = (a < b) ? a : b, dhi = (a < b) ? b : a;
          unsigned pid = (dlo << 16) | dhi;
          unsigned long long packed = ((unsigned long long)ev << 32) | pid;
          unsigned h = (pid * 2654435761u) >> 19;
          for (int t = 0; t < HSZ; ++t) {
            unsigned long long cur = tab[h];
            if (cur == 0ull) {
              unsigned long long old = atomicCAS(&tab[h], 0ull, packed);
              if (old == 0ull) break;
              cur = old;
            }
            if ((unsigned)cur == pid) { atomicMax(&tab[h], packed); break; }
            h = (h + 1) & (HSZ - 1);
          }
        }
      }
    }
  }
}

// ---------------------------------------------------------------------------
// Kernel 5: HALF-sort. 2 blocks/problem; each gathers + radix-sorts its half
// of the hash table in LDS, writes the sorted run back to its half of TAB.
// ---------------------------------------------------------------------------
__global__ __launch_bounds__(ST) void sort_half_k(float* ws) {
  __shared__ unsigned keyA[HHALF], payA[HHALF];  // 32KB
  __shared__ unsigned keyB[HHALF], payB[HHALF];  // 32KB
  __shared__ unsigned short cofs[16 * ST];       // 16KB
  __shared__ unsigned wtot[8 * 16];
  __shared__ unsigned tot[16], stot[16];
  __shared__ unsigned mc_sh;
  __shared__ int skip_sh;
  int p = blockIdx.x >> 1, h = blockIdx.x & 1, tid = threadIdx.x;
  int wave = tid >> 6, lane = tid & 63;
  unsigned long long* tab = (unsigned long long*)((char*)ws + OFF_TAB) + (size_t)p * HSZ + (size_t)h * HHALF;
  unsigned* c2 = (unsigned*)((char*)ws + OFF_C2);
  // gather (scan compaction)
  const int GS = HHALF / ST;                     // 8 slots each
  int g0 = tid * GS;
  unsigned mn = 0;
  for (int i = g0; i < g0 + GS; ++i) mn += (tab[i] != 0ull) ? 1u : 0u;
  unsigned ginc = mn;
  #pragma unroll
  for (int off = 1; off < 64; off <<= 1) {
    unsigned v = __shfl_up(ginc, off);
    if (lane >= off) ginc += v;
  }
  if (lane == 63) wtot[wave] = ginc;
  __syncthreads();
  if (tid == 0) {
    unsigned run = 0;
    for (int w = 0; w < 8; ++w) { unsigned t = wtot[w]; wtot[w] = run; run += t; }
    mc_sh = run;
  }
  __syncthreads();
  {
    unsigned base = wtot[wave] + ginc - mn;
    for (int i = g0; i < g0 + GS; ++i) {
      unsigned long long x = tab[i];
      if (x != 0ull) { keyA[base] = (unsigned)(x >> 32); payA[base] = (unsigned)x; ++base; }
    }
  }
  unsigned E = mc_sh;
  __syncthreads();
  unsigned chunk = (E + ST - 1) / ST;
  unsigned lo = tid * chunk; if (lo > E) lo = E;
  unsigned hi = lo + chunk; if (hi > E) hi = E;
  bool srcA = true;
  for (int pass = 0; pass < 8; ++pass) {
    int shift = pass * 4;
    const unsigned* sk = srcA ? keyA : keyB;
    const unsigned* sp = srcA ? payA : payB;
    unsigned* dk = srcA ? keyB : keyA;
    unsigned* dp = srcA ? payB : payA;
    unsigned myc[16];
    #pragma unroll
    for (int s = 0; s < 16; ++s) myc[s] = 0;
    for (unsigned i = lo; i < hi; ++i) {
      unsigned slot = 15u - ((sk[i] >> shift) & 15u);
      #pragma unroll
      for (int s = 0; s < 16; ++s) myc[s] += (slot == (unsigned)s) ? 1u : 0u;
    }
    unsigned incl[16];
    #pragma unroll
    for (int s = 0; s < 16; ++s) incl[s] = myc[s];
    #pragma unroll
    for (int off = 1; off < 64; off <<= 1) {
      #pragma unroll
      for (int s = 0; s < 16; ++s) {
        unsigned v = __shfl_up(incl[s], off);
        if (lane >= off) incl[s] += v;
      }
    }
    if (lane == 63) {
      #pragma unroll
      for (int s = 0; s < 16; ++s) wtot[wave * 16 + s] = incl[s];
    }
    __syncthreads();
    if (tid < 16) {
      unsigned run = 0;
      for (int w = 0; w < 8; ++w) {
        unsigned t = wtot[w * 16 + tid];
        wtot[w * 16 + tid] = run;
        run += t;
      }
      tot[tid] = run;
    }
    __syncthreads();
    if (tid == 0) {
      int sk2 = 0; unsigned s_ = 0;
      for (int d = 0; d < 16; ++d) { unsigned c = tot[d]; if (c == E) sk2 = 1; stot[d] = s_; s_ += c; }
      skip_sh = sk2;
    }
    __syncthreads();
    if (skip_sh) continue;
    #pragma unroll
    for (int s = 0; s < 16; ++s)
      cofs[s * ST + tid] = (unsigned short)(stot[s] + wtot[wave * 16 + s] + incl[s] - myc[s]);
    for (unsigned i = lo; i < hi; ++i) {
      unsigned k = sk[i];
      unsigned slot = 15u - ((k >> shift) & 15u);
      unsigned a = slot * ST + tid;
      unsigned off = cofs[a]; cofs[a] = (unsigned short)(off + 1u);
      dk[off] = k; dp[off] = sp[i];
    }
    __syncthreads();
    srcA = !srcA;
  }
  const unsigned* fk = srcA ? keyA : keyB;
  const unsigned* fp = srcA ? payA : payB;
  for (unsigned i = tid; i < E; i += ST)
    tab[i] = ((unsigned long long)fk[i] << 32) | fp[i];
  if (tid == 0) c2[p * 2 + h] = E;
}

// ---------------------------------------------------------------------------
// Kernel 6: merge-path (unique u64 keys, no ties) + prefix-CC snapshots.
// One block/problem. Merged edges -> TAB[0..E); pids kept in LDS for CC.
// ---------------------------------------------------------------------------
__global__ __launch_bounds__(ST) void mergecc_k(float* ws) {
  __shared__ unsigned kA[HHALF], pA[HHALF];     // 32KB
  __shared__ unsigned kBv[HHALF], pBv[HHALF];   // 32KB
  __shared__ unsigned payM[HSZ];                // 32KB
  __shared__ unsigned par[RCAP];                // 12KB
  int p = blockIdx.x, tid = threadIdx.x;
  unsigned long long* tab = (unsigned long long*)((char*)ws + OFF_TAB) + (size_t)p * HSZ;
  unsigned short* state = (unsigned short*)((char*)ws + OFF_STATE) + (size_t)p * SNAPN * RCAP;
  unsigned* ecnt = (unsigned*)((char*)ws + OFF_ECNT);
  const unsigned* rcnt = (const unsigned*)((const char*)ws + OFF_RCNT);
  const unsigned* c2 = (const unsigned*)((const char*)ws + OFF_C2);
  unsigned R = rcnt[p]; if (R > RCAP) R = RCAP;
  unsigned cA = c2[p * 2], cB = c2[p * 2 + 1];
  unsigned E = cA + cB;
  for (unsigned i = tid; i < cA; i += ST) {
    unsigned long long x = tab[i];
    kA[i] = (unsigned)(x >> 32); pA[i] = (unsigned)x;
  }
  for (unsigned i = tid; i < cB; i += ST) {
    unsigned long long x = tab[HHALF + i];
    kBv[i] = (unsigned)(x >> 32); pBv[i] = (unsigned)x;
  }
  __syncthreads();
  // merge-path: each thread emits [k0,k1)
  unsigned seg = (E + ST - 1) / ST;
  unsigned k0 = tid * seg; if (k0 > E) k0 = E;
  unsigned k1 = k0 + seg; if (k1 > E) k1 = E;
  unsigned loI = (k0 > cB) ? (k0 - cB) : 0u;
  unsigned hiI = (k0 < cA) ? k0 : cA;
  while (loI < hiI) {
    unsigned mid = (loI + hiI) >> 1;
    unsigned long long a = ((unsigned long long)kA[mid] << 32) | pA[mid];
    unsigned bj = k0 - mid - 1;
    unsigned long long b = ((unsigned long long)kBv[bj] << 32) | pBv[bj];
    if (a > b) loI = mid + 1; else hiI = mid;
  }
  unsigned i = loI, j = k0 - loI;
  for (unsigned k = k0; k < k1; ++k) {
    bool takeA;
    if (j >= cB) takeA = true;
    else if (i >= cA) takeA = false;
    else {
      unsigned long long a = ((unsigned long long)kA[i] << 32) | pA[i];
      unsigned long long b = ((unsigned long long)kBv[j] << 32) | pBv[j];
      takeA = (a > b);
    }
    unsigned kk = takeA ? kA[i] : kBv[j];
    unsigned pp = takeA ? pA[i] : pBv[j];
    if (takeA) ++i; else ++j;
    tab[k] = ((unsigned long long)kk << 32) | pp;
    payM[k] = pp;
  }
  if (tid == 0) ecnt[p] = E;
  __syncthreads();
  // prefix-CC snapshots (pids from LDS)
  for (unsigned d = tid; d < R; d += ST) par[d] = d;
  __syncthreads();
  volatile unsigned* vpar = par;
  unsigned cp = (E + KB - 1) / KB;
  for (int s = 0; s < SNAPN; ++s) {
    for (unsigned d = tid; d < R; d += ST) {
      unsigned r = d;
      while (vpar[r] != r) r = vpar[r];
      par[d] = r;
      state[s * RCAP + d] = (unsigned short)r;
    }
    __syncthreads();
    unsigned e0 = (unsigned)s * 8u * cp; if (e0 > E) e0 = E;
    unsigned e1 = (unsigned)(s + 1) * 8u * cp; if (e1 > E) e1 = E;
    for (unsigned e = e0 + tid; e < e1; e += ST) {
      unsigned pid = payM[e];
      uf_union(vpar, par, pid >> 16, pid & 0xffffu);
    }
    __syncthreads();
  }
}

// ---------------------------------------------------------------------------
// Kernel 7: bucketed Kruskal with speculative root hints.
// ---------------------------------------------------------------------------
__global__ __launch_bounds__(256) void kruskal_bucket_k(float* ws) {
  __shared__ unsigned par[RCAP];
  __shared__ unsigned hintR[MYCAP];
  __shared__ unsigned hintE[MYCAP];
  __shared__ float    hintB[MYCAP];
  __shared__ float    barbuf[MYCAP];
  __shared__ unsigned nb_sh, base_sh;
  int p = blockIdx.x / KB, bk = blockIdx.x % KB, tid = threadIdx.x;
  const unsigned long long* gedges = (const unsigned long long*)((const char*)ws + OFF_TAB) + (size_t)p * HSZ;
  const float* d2b = (const float*)((const char*)ws + OFF_D2B) + (size_t)p * RCAP;
  const unsigned short* state = (const unsigned short*)((const char*)ws + OFF_STATE) + (size_t)p * SNAPN * RCAP + (size_t)(bk >> 3) * RCAP;
  const unsigned* ecnt = (const unsigned*)((const char*)ws + OFF_ECNT);
  const unsigned* rcnt = (const unsigned*)((const char*)ws + OFF_RCNT);
  unsigned* lcnt = (unsigned*)((char*)ws + OFF_LCNT);
  float* glist = (float*)((char*)ws + OFF_LIST) + (size_t)p * LISTCAP;
  unsigned E = ecnt[p]; if (E > HSZ) E = HSZ;
  unsigned R = rcnt[p]; if (R > RCAP) R = RCAP;
  unsigned cp = (E + KB - 1) / KB;
  unsigned rep_lo = (unsigned)(bk & ~7) * cp; if (rep_lo > E) rep_lo = E;
  unsigned own_lo = (unsigned)bk * cp;        if (own_lo > E) own_lo = E;
  unsigned own_hi = own_lo + cp;              if (own_hi > E) own_hi = E;
  unsigned mc = own_hi - own_lo;
  for (unsigned d = tid; d < R; d += 256) par[d] = state[d];
  __syncthreads();
  volatile unsigned* vpar = par;
  for (unsigned e = rep_lo + tid; e < own_lo; e += 256) {
    unsigned pid = (unsigned)gedges[e];
    uf_union(vpar, par, pid >> 16, pid & 0xffffu);
  }
  __syncthreads();
  for (unsigned d = tid; d < R; d += 256) {
    unsigned r = d;
    while (vpar[r] != r) r = vpar[r];
    par[d] = r;
  }
  __syncthreads();
  if (tid < mc) {
    unsigned long long it = gedges[own_lo + tid];
    unsigned pid = (unsigned)it;
    unsigned ra = par[pid >> 16];
    unsigned rb = par[pid & 0xffffu];
    hintR[tid] = (ra << 16) | rb;
    hintE[tid] = (unsigned)(it >> 32);
    hintB[tid] = d2b[(ra > rb) ? ra : rb];
  }
  __syncthreads();
  if (tid >= 64) return;
  const int lane = tid;
  if (lane == 0) {
    unsigned nb = 0;
    for (unsigned e = 0; e < mc; ++e) {
      unsigned h = hintR[e];
      unsigned ra = h >> 16, rb = h & 0xffffu;
      if (ra == rb) continue;
      unsigned ca = ra, pa = par[ca];
      while (pa != ca) { unsigned ga = par[pa]; par[ca] = ga; ca = ga; pa = par[ca]; }
      unsigned cb = rb, pb = par[cb];
      while (pb != cb) { unsigned gb = par[pb]; par[cb] = gb; cb = gb; pb = par[cb]; }
      if (ca == cb) continue;
      unsigned win = (ca < cb) ? ca : cb;
      unsigned los = (ca < cb) ? cb : ca;
      float birth = (ca == ra && cb == rb) ? hintB[e] : d2b[los];
      barbuf[nb++] = birth - unmono(hintE[e]);
      par[los] = win;
    }
    nb_sh = nb;
  }
  __asm__ volatile("s_waitcnt lgkmcnt(0)" ::: "memory");
  __builtin_amdgcn_wave_barrier();
  if (lane == 0) base_sh = atomicAdd(&lcnt[p], nb_sh);
  __asm__ volatile("s_waitcnt vmcnt(0) lgkmcnt(0)" ::: "memory");
  __builtin_amdgcn_wave_barrier();
  unsigned nb = nb_sh, base = base_sh;
  for (unsigned i = lane; i < nb; i += 64) {
    unsigned idx = base + i;
    if (idx < LISTCAP) glist[idx] = barbuf[i];
  }
}

// ---------------------------------------------------------------------------
// Kernel 8: per-problem top-20 (wave-shuffle reduction) + fused final mean.
// ---------------------------------------------------------------------------
__global__ __launch_bounds__(256) void topk_k(float* ws, float* out) {
  __shared__ float sl[LISTCAP];
  __shared__ float wval[4];
  __shared__ int   widx[4];
  int p = blockIdx.x, tid = threadIdx.x;
  const float* glist = (const float*)((const char*)ws + OFF_LIST) + (size_t)p * LISTCAP;
  const unsigned* lcnt = (const unsigned*)((const char*)ws + OFF_LCNT);
  unsigned cnt = lcnt[p]; if (cnt > LISTCAP) cnt = LISTCAP;
  for (unsigned i = tid; i < cnt; i += 256) sl[i] = glist[i];
  __syncthreads();
  float acc = 0.f;
  for (int k = 0; k < K_TOP; ++k) {
    float mv = -1.f; int mi = LISTCAP;
    for (unsigned i = tid; i < cnt; i += 256) {
      float v = sl[i];
      if (v > mv) { mv = v; mi = (int)i; }
    }
    #pragma unroll
    for (int off = 32; off >= 1; off >>= 1) {
      float ov = __shfl_down(mv, off);
      int   oi = __shfl_down(mi, off);
      if (ov > mv || (ov == mv && oi < mi)) { mv = ov; mi = oi; }
    }
    if ((tid & 63) == 0) { wval[tid >> 6] = mv; widx[tid >> 6] = mi; }
    __syncthreads();
    if (tid == 0) {
      float bv = wval[0]; int bi = widx[0];
      #pragma unroll
      for (int w = 1; w < 4; ++w) {
        if (wval[w] > bv || (wval[w] == bv && widx[w] < bi)) { bv = wval[w]; bi = widx[w]; }
      }
      float best = bv > 0.f ? bv : 0.f;
      float sgnk = (k < 5) ? -1.f : 1.f;
      acc += sgnk * best * best;
      if (bi < LISTCAP) sl[bi] = -2.f;
    }
    __syncthreads();
  }
  if (tid == 0) atomicAdd(out, acc * (1.f / (float)NB));
}

extern "C" void kernel_launch(void* const* d_in, const int* in_sizes, int n_in,
                              void* d_out, int out_size, void* d_ws, size_t ws_size,
                              hipStream_t stream) {
  const float* in = (const float*)d_in[0];
  float* ws = (float*)d_ws;
  float* out = (float*)d_out;
  hipLaunchKernelGGL(resize_init_k, dim3(RBLK + NPROB), dim3(256), 0, stream, in, ws, out);
  hipLaunchKernelGGL(spnchase_k, dim3(NPROB), dim3(ST), 0, stream, ws);
  hipLaunchKernelGGL(rank_root_k, dim3(NPROB * 16), dim3(256), 0, stream, ws);
  hipLaunchKernelGGL(hash_k, dim3(NPROB * 16), dim3(256), 0, stream, ws);
  hipLaunchKernelGGL(sort_half_k, dim3(NPROB * 2), dim3(ST), 0, stream, ws);
  hipLaunchKernelGGL(mergecc_k, dim3(NPROB), dim3(ST), 0, stream, ws);
  hipLaunchKernelGGL(kruskal_bucket_k, dim3(NPROB * KB), dim3(256), 0, stream, ws);
  hipLaunchKernelGGL(topk_k, dim3(NPROB), dim3(256), 0, stream, ws, out);
}